// Round 18
// baseline (161.592 us; speedup 1.0000x reference)
//
#include <hip/hip_runtime.h>
#include <hip/hip_bf16.h>
#include <math.h>

#define GG 8192
#define AA 5
#define NN (GG * AA)        // 40960
#define DD 512

typedef unsigned short ushort_t;
typedef unsigned int uint_t;

__device__ inline float bf2f(ushort_t u) {
  union { uint_t i; float f; } c; c.i = ((uint_t)u) << 16; return c.f;
}
__device__ inline ushort_t f2bf(float f) {
  union { float f; uint_t i; } c; c.f = f;
  uint_t r = c.i + 0x7fffu + ((c.i >> 16) & 1u);   // round-to-nearest-even
  return (ushort_t)(r >> 16);
}

using frag8 = __attribute__((ext_vector_type(8))) short;
using f32x4 = __attribute__((ext_vector_type(4))) float;

typedef __attribute__((address_space(3))) void lds_void;
typedef __attribute__((address_space(1))) const void gbl_void;
#define GLL(g, l) __builtin_amdgcn_global_load_lds((gbl_void*)(g), (lds_void*)(l), 16, 0, 0)

// XCD-chunked bijective swizzle (requires nwg % 8 == 0).
__device__ inline int xcd_swz(int bid, int nwg) {
  return (bid & 7) * (nwg >> 3) + (bid >> 3);
}

// ---------------------------------------------------------------------------
// Prep (grid = 1024 + 5120): weight packs + score-weight folds wsc = W @ a.
// wscT layout [16 score-col][K]; score-col s: head = s>>1, which = s&1
// (0 = a_s, 1 = a_d).
// ---------------------------------------------------------------------------
__global__ __launch_bounds__(256) void k_prep(
    const float* __restrict__ x, const float* __restrict__ W1,
    const float* __restrict__ W2, const float* __restrict__ pw1,
    const float* __restrict__ qw1, const float* __restrict__ tw1,
    const float* __restrict__ aw1, const float* __restrict__ pb1,
    const float* __restrict__ qb1, const float* __restrict__ tb1,
    const float* __restrict__ ab1, const float* __restrict__ We1,
    const float* __restrict__ ae1, const float* __restrict__ We2,
    const float* __restrict__ ae2, const float* __restrict__ as1,
    const float* __restrict__ ad1, const float* __restrict__ as2,
    const float* __restrict__ ad2, const float* __restrict__ pw2,
    const float* __restrict__ pb2, const float* __restrict__ qw2,
    const float* __restrict__ qb2, const float* __restrict__ tw2,
    const float* __restrict__ tb2, const float* __restrict__ aw2,
    const float* __restrict__ ab2, ushort_t* __restrict__ xpad32,
    ushort_t* __restrict__ W1T32, ushort_t* __restrict__ W2T,
    ushort_t* __restrict__ WcatT, ushort_t* __restrict__ aw1topT,
    ushort_t* __restrict__ wsc1T, ushort_t* __restrict__ wsc2T,
    float* __restrict__ bcat, float* __restrict__ sce,
    float* __restrict__ woutT, float* __restrict__ bout) {
  int b = blockIdx.x;
  int t = threadIdx.x;
  if (b < 1024) {
    int i = b * 256 + t;            // 0 .. 262143
    int n = i >> 9, k = i & 511;
    W2T[(size_t)n * 512 + k] = f2bf(W2[(size_t)k * 512 + n]);
    float v;
    if (n < 128)      v = pw1[(size_t)k * 128 + n];
    else if (n < 256) v = qw1[(size_t)k * 128 + (n - 128)];
    else if (n < 320) v = tw1[(size_t)k * 64 + (n - 256)];
    else if (n < 448) v = aw1[(size_t)(512 + k) * 128 + (n - 320)];
    else              v = 0.f;
    WcatT[(size_t)n * 512 + k] = f2bf(v);
    if (n < 128) aw1topT[(size_t)n * 512 + k] = f2bf(aw1[(size_t)k * 128 + n]);
    if (k == 0) {
      float bv;
      if (n < 128)      bv = pb1[n];
      else if (n < 256) bv = qb1[n - 128];
      else if (n < 320) bv = tb1[n - 256];
      else if (n < 448) bv = ab1[n - 320];
      else              bv = 0.f;
      bcat[n] = bv;
    }
    if (i < 512 * 32) {
      int nn = i >> 5, kk = i & 31;
      W1T32[i] = (kk < 29) ? f2bf(W1[(size_t)kk * 512 + nn]) : (ushort_t)0;
    }
    // wsc2T: [16][512]
    if (i < 8192) {
      int k2 = i & 511, s = i >> 9;
      int head = s >> 1;
      const float* av = ((s & 1) ? ad2 : as2) + head * 64;
      const float* wr = W2 + (size_t)k2 * 512 + head * 64;
      float val = 0.f;
      for (int c = 0; c < 64; ++c) val = fmaf(wr[c], av[c], val);
      wsc2T[i] = f2bf(val);
    }
    // wsc1T: [16][32]
    if (i < 512) {
      int k1 = i & 31, s = i >> 5;
      int head = s >> 1;
      float val = 0.f;
      if (k1 < 29) {
        const float* av = ((s & 1) ? ad1 : as1) + head * 64;
        const float* wr = W1 + (size_t)k1 * 512 + head * 64;
        for (int c = 0; c < 64; ++c) val = fmaf(wr[c], av[c], val);
      }
      wsc1T[i] = f2bf(val);
    }
    if (i < 16) {
      int h = i & 7;
      const float* Wp = (i < 8) ? We1 : We2;
      const float* ap = (i < 8) ? ae1 : ae2;
      float c = 0.f;
      for (int k2 = 0; k2 < 64; ++k2) c = fmaf(Wp[h * 64 + k2], ap[h * 64 + k2], c);
      sce[i] = c;
    }
    if (i < 5120) {
      int j = i / 40, o = i % 40;
      float wv;
      if (o < 4)       wv = pw2[j * 4 + o];
      else if (o < 8)  wv = qw2[j * 4 + (o - 4)];
      else if (o == 8) wv = (j < 64) ? tw2[j] : 0.f;
      else if (o < 24) wv = aw2[j * 6 + (o - 9) % 3];
      else if (o < 39) wv = aw2[j * 6 + 3 + (o - 24) % 3];
      else             wv = 0.f;
      woutT[i] = wv;
      if (j == 0) {
        float bv;
        if (o < 4)       bv = pb2[o];
        else if (o < 8)  bv = qb2[o - 4];
        else if (o == 8) bv = tb2[0];
        else if (o < 24) bv = ab2[(o - 9) % 3];
        else if (o < 39) bv = ab2[3 + (o - 24) % 3];
        else             bv = 0.f;
        bout[o] = bv;
      }
    }
  } else {
    int i = (b - 1024) * 256 + t;   // 0 .. 1310719
    int n = i >> 5, k = i & 31;
    xpad32[i] = (k < 29) ? f2bf(x[(size_t)n * 29 + k]) : (ushort_t)0;
  }
}

// ---------------------------------------------------------------------------
// MEGA-FUSED: both GAT layers for 16 graphs in one block; h1 never leaves LDS.
// 1024 threads = 16 waves; wave w owns cols [w*32, w*32+32) (2 n-tiles);
// wave 15 additionally computes the 16-col score tile (8 heads x {s,d}).
// Phase 1: L1 GEMM (single K-tile, GLL-staged) + scores + alpha + combine ->
//   h1 written INTO LDS in the XOR-swizzled A-fragment chunk layout.
// Phase 2: BARRIER-FREE K-loop. B (W2T, L2-resident 0.5MB) and the score
//   weights stream global->register with a named 2-deep pipeline (compiler
//   scoreboards the waits); A-frags read from read-only h1buf. No LDS B
//   staging, no vmcnt asm, no s_barrier in the loop -> waves free-run.
// LDS map: h1buf @0 (81920); P1 staging: W1T32 @81920, A1 @114688, S1
//   @119808; epilogues: Hbf @81920 (42240), sal @124160, sss @136960,
//   ssd @139520 (end 142080).
// ---------------------------------------------------------------------------
__global__ __launch_bounds__(1024) void k_mega(
    const ushort_t* __restrict__ xpad32, const ushort_t* __restrict__ W1T32,
    const ushort_t* __restrict__ wsc1T, const ushort_t* __restrict__ W2T,
    const ushort_t* __restrict__ wsc2T, const float* __restrict__ eattr,
    const float* __restrict__ sce, const float* __restrict__ b1,
    const float* __restrict__ b2, ushort_t* __restrict__ h2,
    ushort_t* __restrict__ gmean) {
  __shared__ __align__(16) char smem[142336];
  const int t = threadIdx.x;
  const int lane = t & 63;
  const int w = t >> 6;                   // 0..15
  const int l15 = lane & 15;
  const int ko2 = ((((lane >> 4) ^ (lane & 3) ^ ((lane >> 2) & 3)) & 3) * 16);
  int lid = xcd_swz(blockIdx.x, gridDim.x);
  const int m0 = lid * 80;
  const int g0 = lid * 16;
  ushort_t* h1buf = (ushort_t*)smem;
  float* sal = (float*)(smem + 124160);   // [80 dst(gi*5+j)][5 src][8 hd]
  float* sss = (float*)(smem + 136960);   // [80][8]
  float* ssd = (float*)(smem + 139520);   // [80][8]
  const f32x4 zz = {0.f, 0.f, 0.f, 0.f};
  f32x4 acc[5][2], asc[5];
#pragma unroll
  for (int mt = 0; mt < 5; ++mt) { acc[mt][0] = zz; acc[mt][1] = zz; asc[mt] = zz; }

  // ================= PHASE 1: layer-1 GEMM (single K-tile) ==================
  {
#pragma unroll
    for (int r_ = 0; r_ < 2; ++r_) {
      int c_ = t + r_ * 1024; int row_ = c_ >> 2;
      int sw_ = ((((c_ & 3) ^ (row_ & 3) ^ ((row_ >> 2) & 3)) & 3)) * 8;
      GLL(W1T32 + (size_t)row_ * 32 + sw_, smem + 81920 + c_ * 16);
    }
    if (t < 320) {
      int c_ = t; int row_ = c_ >> 2;
      int sw_ = ((((c_ & 3) ^ (row_ & 3) ^ ((row_ >> 2) & 3)) & 3)) * 8;
      GLL(xpad32 + (size_t)(m0 + row_) * 32 + sw_, smem + 114688 + c_ * 16);
    } else if (t < 384) {
      int c_ = t - 320; int row_ = c_ >> 2;
      int sw_ = ((((c_ & 3) ^ (row_ & 3) ^ ((row_ >> 2) & 3)) & 3)) * 8;
      GLL(wsc1T + (size_t)row_ * 32 + sw_, smem + 119808 + c_ * 16);
    }
  }
  asm volatile("s_waitcnt vmcnt(0)" ::: "memory");
  __builtin_amdgcn_s_barrier();
  {
    const char* bb = smem + 81920;
    const char* aa = smem + 114688;
    const char* sb = smem + 119808;
    frag8 af[5], bfr[2];
#pragma unroll
    for (int mt = 0; mt < 5; ++mt)
      af[mt] = *(const frag8*)(aa + (mt * 16 + l15) * 64 + ko2);
#pragma unroll
    for (int n = 0; n < 2; ++n)
      bfr[n] = *(const frag8*)(bb + ((2 * w + n) * 16 + l15) * 64 + ko2);
#pragma unroll
    for (int mt = 0; mt < 5; ++mt)
#pragma unroll
      for (int n = 0; n < 2; ++n)
        acc[mt][n] = __builtin_amdgcn_mfma_f32_16x16x32_bf16(af[mt], bfr[n], acc[mt][n], 0, 0, 0);
    if (w == 15) {
      frag8 sfr = *(const frag8*)(sb + l15 * 64 + ko2);
#pragma unroll
      for (int mt = 0; mt < 5; ++mt)
        asc[mt] = __builtin_amdgcn_mfma_f32_16x16x32_bf16(af[mt], sfr, asc[mt], 0, 0, 0);
    }
  }
  if (w == 15) {
    float* dst = (l15 & 1) ? ssd : sss;
    int hd = l15 >> 1;
    int q4 = (lane >> 4) * 4;
#pragma unroll
    for (int mt = 0; mt < 5; ++mt)
#pragma unroll
      for (int r = 0; r < 4; ++r)
        dst[(mt * 16 + q4 + r) * 8 + hd] = asc[mt][r];
  }
  __syncthreads();
  // alpha-1: 640 units (gi, dst j, hd)
  if (t < 640) {
    int gi = t / 40, jh = t % 40;
    int j = jh >> 3, hd = jh & 7;
    int g = g0 + gi;
    float sdj = ssd[(gi * 5 + j) * 8 + hd];
    float ce = sce[hd];
    float lg[5], mx = -1e30f;
#pragma unroll
    for (int i = 0; i < 5; ++i) {
      float l = sss[(gi * 5 + i) * 8 + hd] + sdj;
      if (i != j) l = fmaf(eattr[(size_t)g * 20 + i * 4 + (j > i ? j - 1 : j)], ce, l);
      l = l > 0.f ? l : 0.2f * l;      // leaky_relu(0.2)
      lg[i] = l; mx = fmaxf(mx, l);
    }
    float s = 0.f;
#pragma unroll
    for (int i = 0; i < 5; ++i) { lg[i] = __expf(lg[i] - mx); s += lg[i]; }
    float inv = 1.f / (s + 1e-16f);
#pragma unroll
    for (int i = 0; i < 5; ++i) sal[((gi * 5 + j) * 5 + i) * 8 + hd] = lg[i] * inv;
  }
  __syncthreads();
  // epilogue-1: 4 passes of 128 cols; combine -> h1buf (LDS, swizzled chunks)
  {
    float* hbf = (float*)(smem + 81920);   // [80][132]
#pragma unroll
    for (int p = 0; p < 4; ++p) {
      if ((w >> 2) == p) {
        int q4 = (lane >> 4) * 4;
#pragma unroll
        for (int mt = 0; mt < 5; ++mt)
#pragma unroll
          for (int n = 0; n < 2; ++n) {
            int lc = (w & 3) * 32 + n * 16 + l15;
#pragma unroll
            for (int r = 0; r < 4; ++r)
              hbf[(mt * 16 + q4 + r) * 132 + lc] = acc[mt][n][r];
          }
      }
      __syncthreads();
      if (t < 512) {
        int gi = t >> 5, cq = t & 31;
        int hd = 2 * p + (cq >> 4);
        int cg = p * 128 + cq * 4;
        float hv[5][4];
#pragma unroll
        for (int i = 0; i < 5; ++i)
          *(float4*)hv[i] = *(const float4*)&hbf[(gi * 5 + i) * 132 + cq * 4];
        float4 bb4 = *(const float4*)&b1[cg];
        int chunk = cg >> 5, slot = (cg >> 3) & 3, boff = (cg & 7) * 2;
#pragma unroll
        for (int j = 0; j < 5; ++j) {
          float o0 = bb4.x, o1 = bb4.y, o2 = bb4.z, o3 = bb4.w;
#pragma unroll
          for (int i = 0; i < 5; ++i) {
            float a = sal[((gi * 5 + j) * 5 + i) * 8 + hd];
            o0 = fmaf(a, hv[i][0], o0); o1 = fmaf(a, hv[i][1], o1);
            o2 = fmaf(a, hv[i][2], o2); o3 = fmaf(a, hv[i][3], o3);
          }
          o0 = fmaxf(o0, 0.f); o1 = fmaxf(o1, 0.f);
          o2 = fmaxf(o2, 0.f); o3 = fmaxf(o3, 0.f);
          uint2 wv_;
          wv_.x = (uint_t)f2bf(o0) | ((uint_t)f2bf(o1) << 16);
          wv_.y = (uint_t)f2bf(o2) | ((uint_t)f2bf(o3) << 16);
          int row = gi * 5 + j;
          int phys = slot ^ (row & 3) ^ ((row >> 2) & 3);
          *(uint2*)((char*)h1buf + chunk * 5120 + row * 64 + phys * 16 + boff) = wv_;
        }
      }
      __syncthreads();
    }
  }

  // ======= PHASE 2: layer-2 GEMM, barrier-free B-streaming (K=512) =========
#pragma unroll
  for (int mt = 0; mt < 5; ++mt) { acc[mt][0] = zz; acc[mt][1] = zz; asc[mt] = zz; }
  {
    const ushort_t* wB0 = W2T + ((size_t)(2 * w + 0) * 16 + l15) * 512 + (lane >> 4) * 8;
    const ushort_t* wB1 = W2T + ((size_t)(2 * w + 1) * 16 + l15) * 512 + (lane >> 4) * 8;
    const ushort_t* wS  = wsc2T + (size_t)l15 * 512 + (lane >> 4) * 8;
    frag8 pbA0 = *(const frag8*)(wB0);
    frag8 pbA1 = *(const frag8*)(wB1);
    frag8 pbB0 = *(const frag8*)(wB0 + 32);
    frag8 pbB1 = *(const frag8*)(wB1 + 32);
    frag8 psA = {}, psB = {};
    if (w == 15) { psA = *(const frag8*)(wS); psB = *(const frag8*)(wS + 32); }
#pragma unroll
    for (int ts = 0; ts < 16; ts += 2) {
      {  // iteration ts (even): consume pbA*, prefetch ts+2
        frag8 c0 = pbA0, c1 = pbA1, cs = psA;
        if (ts + 2 < 16) {
          pbA0 = *(const frag8*)(wB0 + (ts + 2) * 32);
          pbA1 = *(const frag8*)(wB1 + (ts + 2) * 32);
          if (w == 15) psA = *(const frag8*)(wS + (ts + 2) * 32);
        }
        const char* aa = (const char*)h1buf + ts * 5120;
        frag8 af[5];
#pragma unroll
        for (int mt = 0; mt < 5; ++mt)
          af[mt] = *(const frag8*)(aa + (mt * 16 + l15) * 64 + ko2);
        __builtin_amdgcn_s_setprio(1);
#pragma unroll
        for (int mt = 0; mt < 5; ++mt) {
          acc[mt][0] = __builtin_amdgcn_mfma_f32_16x16x32_bf16(af[mt], c0, acc[mt][0], 0, 0, 0);
          acc[mt][1] = __builtin_amdgcn_mfma_f32_16x16x32_bf16(af[mt], c1, acc[mt][1], 0, 0, 0);
        }
        if (w == 15) {
#pragma unroll
          for (int mt = 0; mt < 5; ++mt)
            asc[mt] = __builtin_amdgcn_mfma_f32_16x16x32_bf16(af[mt], cs, asc[mt], 0, 0, 0);
        }
        __builtin_amdgcn_s_setprio(0);
      }
      {  // iteration ts+1 (odd): consume pbB*, prefetch ts+3
        frag8 c0 = pbB0, c1 = pbB1, cs = psB;
        if (ts + 3 < 16) {
          pbB0 = *(const frag8*)(wB0 + (ts + 3) * 32);
          pbB1 = *(const frag8*)(wB1 + (ts + 3) * 32);
          if (w == 15) psB = *(const frag8*)(wS + (ts + 3) * 32);
        }
        const char* aa = (const char*)h1buf + (ts + 1) * 5120;
        frag8 af[5];
#pragma unroll
        for (int mt = 0; mt < 5; ++mt)
          af[mt] = *(const frag8*)(aa + (mt * 16 + l15) * 64 + ko2);
        __builtin_amdgcn_s_setprio(1);
#pragma unroll
        for (int mt = 0; mt < 5; ++mt) {
          acc[mt][0] = __builtin_amdgcn_mfma_f32_16x16x32_bf16(af[mt], c0, acc[mt][0], 0, 0, 0);
          acc[mt][1] = __builtin_amdgcn_mfma_f32_16x16x32_bf16(af[mt], c1, acc[mt][1], 0, 0, 0);
        }
        if (w == 15) {
#pragma unroll
          for (int mt = 0; mt < 5; ++mt)
            asc[mt] = __builtin_amdgcn_mfma_f32_16x16x32_bf16(af[mt], cs, asc[mt], 0, 0, 0);
        }
        __builtin_amdgcn_s_setprio(0);
      }
    }
  }
  // scores spill
  if (w == 15) {
    float* dst = (l15 & 1) ? ssd : sss;
    int hd = l15 >> 1;
    int q4 = (lane >> 4) * 4;
#pragma unroll
    for (int mt = 0; mt < 5; ++mt)
#pragma unroll
      for (int r = 0; r < 4; ++r)
        dst[(mt * 16 + q4 + r) * 8 + hd] = asc[mt][r];
  }
  __syncthreads();
  // alpha-2
  if (t < 640) {
    int gi = t / 40, jh = t % 40;
    int j = jh >> 3, hd = jh & 7;
    int g = g0 + gi;
    float sdj = ssd[(gi * 5 + j) * 8 + hd];
    float ce = sce[8 + hd];
    float lg[5], mx = -1e30f;
#pragma unroll
    for (int i = 0; i < 5; ++i) {
      float l = sss[(gi * 5 + i) * 8 + hd] + sdj;
      if (i != j) l = fmaf(eattr[(size_t)g * 20 + i * 4 + (j > i ? j - 1 : j)], ce, l);
      l = l > 0.f ? l : 0.2f * l;
      lg[i] = l; mx = fmaxf(mx, l);
    }
    float s = 0.f;
#pragma unroll
    for (int i = 0; i < 5; ++i) { lg[i] = __expf(lg[i] - mx); s += lg[i]; }
    float inv = 1.f / (s + 1e-16f);
#pragma unroll
    for (int i = 0; i < 5; ++i) sal[((gi * 5 + j) * 5 + i) * 8 + hd] = lg[i] * inv;
  }
  __syncthreads();
  // epilogue-2: 4 passes of 128 cols; combine -> h2 + gmean (global)
  {
    float* hbf = (float*)(smem + 81920);   // [80][132]
#pragma unroll
    for (int p = 0; p < 4; ++p) {
      if ((w >> 2) == p) {
        int q4 = (lane >> 4) * 4;
#pragma unroll
        for (int mt = 0; mt < 5; ++mt)
#pragma unroll
          for (int n = 0; n < 2; ++n) {
            int lc = (w & 3) * 32 + n * 16 + l15;
#pragma unroll
            for (int r = 0; r < 4; ++r)
              hbf[(mt * 16 + q4 + r) * 132 + lc] = acc[mt][n][r];
          }
      }
      __syncthreads();
      if (t < 512) {
        int gi = t >> 5, cq = t & 31;
        int hd = 2 * p + (cq >> 4);
        int cg = p * 128 + cq * 4;
        float hv[5][4];
#pragma unroll
        for (int i = 0; i < 5; ++i)
          *(float4*)hv[i] = *(const float4*)&hbf[(gi * 5 + i) * 132 + cq * 4];
        float4 bb4 = *(const float4*)&b2[cg];
        float gs0 = 0.f, gs1 = 0.f, gs2 = 0.f, gs3 = 0.f;
#pragma unroll
        for (int j = 0; j < 5; ++j) {
          float o0 = bb4.x, o1 = bb4.y, o2 = bb4.z, o3 = bb4.w;
#pragma unroll
          for (int i = 0; i < 5; ++i) {
            float a = sal[((gi * 5 + j) * 5 + i) * 8 + hd];
            o0 = fmaf(a, hv[i][0], o0); o1 = fmaf(a, hv[i][1], o1);
            o2 = fmaf(a, hv[i][2], o2); o3 = fmaf(a, hv[i][3], o3);
          }
          o0 = fmaxf(o0, 0.f); o1 = fmaxf(o1, 0.f);
          o2 = fmaxf(o2, 0.f); o3 = fmaxf(o3, 0.f);
          uint2 wv_;
          wv_.x = (uint_t)f2bf(o0) | ((uint_t)f2bf(o1) << 16);
          wv_.y = (uint_t)f2bf(o2) | ((uint_t)f2bf(o3) << 16);
          *(uint2*)(h2 + ((size_t)(g0 + gi) * 5 + j) * 512 + cg) = wv_;
          gs0 += o0; gs1 += o1; gs2 += o2; gs3 += o3;
        }
        uint2 wv_;
        wv_.x = (uint_t)f2bf(gs0 * 0.2f) | ((uint_t)f2bf(gs1 * 0.2f) << 16);
        wv_.y = (uint_t)f2bf(gs2 * 0.2f) | ((uint_t)f2bf(gs3 * 0.2f) << 16);
        *(uint2*)(gmean + (size_t)(g0 + gi) * 512 + cg) = wv_;
      }
      __syncthreads();
    }
  }
}

// ---------------------------------------------------------------------------
// bf16 MFMA GEMM body — unchanged; used by the head GEMMs.
// EPI: 1 = f32 out; 2 = f32 out + bias + relu(col<320)
// ---------------------------------------------------------------------------
template <int EPI>
__device__ __forceinline__ void gemm_body(
    const ushort_t* __restrict__ A, const ushort_t* __restrict__ BT,
    const float* __restrict__ bias, void* __restrict__ Cv,
    int M, int N, int K, int m0, int n0, char* lds) {
  int t = threadIdx.x;
  int lane = t & 63;
  int wv = t >> 6;
  int wr = (wv >> 1) * 64, wc = (wv & 1) * 64;
  f32x4 acc[4][4] = {};
  int ch0 = t, ch1 = t + 256;
  int row0 = ch0 >> 2, row1 = ch1 >> 2;
  int sw0 = (((ch0 & 3) ^ (row0 & 3) ^ ((row0 >> 2) & 3)) & 3) * 8;
  int sw1 = (((ch1 & 3) ^ (row1 & 3) ^ ((row1 >> 2) & 3)) & 3) * 8;
  int ko2 = ((((lane >> 4) ^ (lane & 3) ^ ((lane >> 2) & 3)) & 3) * 16);
  const int nt = K >> 5;
#define STAGE(bi, kk0)                                                         \
  {                                                                            \
    char* ab = lds + (bi) * 16384;                                             \
    GLL(A + (size_t)(m0 + row0) * K + (kk0) + sw0, ab + ch0 * 16);             \
    GLL(A + (size_t)(m0 + row1) * K + (kk0) + sw1, ab + ch1 * 16);             \
    GLL(BT + (size_t)(n0 + row0) * K + (kk0) + sw0, ab + 8192 + ch0 * 16);     \
    GLL(BT + (size_t)(n0 + row1) * K + (kk0) + sw1, ab + 8192 + ch1 * 16);     \
  }
  STAGE(0, 0);
  if (nt > 1) STAGE(1, 32);
  for (int ts = 0; ts < nt; ++ts) {
    int bi = ts % 3;
    if (ts + 2 < nt) {
      STAGE((ts + 2) % 3, (ts + 2) * 32);
      asm volatile("s_waitcnt vmcnt(8)" ::: "memory");
    } else if (ts + 1 < nt) {
      asm volatile("s_waitcnt vmcnt(4)" ::: "memory");
    } else {
      asm volatile("s_waitcnt vmcnt(0)" ::: "memory");
    }
    __builtin_amdgcn_s_barrier();
    __builtin_amdgcn_sched_barrier(0);
    const char* ab = lds + bi * 16384;
    frag8 af[4], bfr[4];
#pragma unroll
    for (int m = 0; m < 4; ++m)
      af[m] = *(const frag8*)(ab + (wr + m * 16 + (lane & 15)) * 64 + ko2);
#pragma unroll
    for (int n = 0; n < 4; ++n)
      bfr[n] = *(const frag8*)(ab + 8192 + (wc + n * 16 + (lane & 15)) * 64 + ko2);
#pragma unroll
    for (int m = 0; m < 4; ++m)
#pragma unroll
      for (int n = 0; n < 4; ++n)
        acc[m][n] = __builtin_amdgcn_mfma_f32_16x16x32_bf16(af[m], bfr[n], acc[m][n], 0, 0, 0);
    __builtin_amdgcn_sched_barrier(0);
    __builtin_amdgcn_s_barrier();
  }
#undef STAGE
  int r4 = (lane >> 4) * 4;
  int cl = lane & 15;
#pragma unroll
  for (int m = 0; m < 4; ++m) {
#pragma unroll
    for (int n = 0; n < 4; ++n) {
      int col = n0 + wc + n * 16 + cl;
      float bb = (EPI == 2) ? bias[col] : 0.f;
#pragma unroll
      for (int r = 0; r < 4; ++r) {
        int row = m0 + wr + m * 16 + r4 + r;
        float v = acc[m][n][r] + bb;
        if (EPI == 2 && col < 320) v = fmaxf(v, 0.f);
        ((float*)Cv)[(size_t)row * N + col] = v;
      }
    }
  }
}

// Fused head GEMMs: blocks [0,320) -> ahid = h2 @ aw1topT^T (f32 out);
// blocks [320,576) -> hcat = gmean @ WcatT^T + bcat, relu(col<320).
__global__ __launch_bounds__(256) void k_hgemm(
    const ushort_t* __restrict__ h2, const ushort_t* __restrict__ aw1topT,
    float* __restrict__ ahid, const ushort_t* __restrict__ gmean,
    const ushort_t* __restrict__ WcatT, const float* __restrict__ bcat,
    float* __restrict__ hcat) {
  __shared__ char lds[49152];
  int bid = blockIdx.x;
  if (bid < 320) {
    int lid = xcd_swz(bid, 320);
    gemm_body<1>(h2, aw1topT, nullptr, ahid, NN, 128, DD, lid * 128, 0, lds);
  } else {
    int lid = xcd_swz(bid - 320, 256);
    gemm_body<2>(gmean, WcatT, bcat, hcat, GG, DD, DD, (lid >> 2) * 128, (lid & 3) * 128, lds);
  }
}

// ---------------------------------------------------------------------------
// Final heads — unchanged.
// ---------------------------------------------------------------------------
__global__ __launch_bounds__(256) void k_heads(
    const float* __restrict__ hcat, const float* __restrict__ ahid,
    const float* __restrict__ woutT, const float* __restrict__ bout,
    const float* __restrict__ alim, float* __restrict__ out) {
  int g0 = blockIdx.x * 4;
  int t = threadIdx.x;
  __shared__ float sbuf[4224];
  for (int i = t; i < 4224; i += 256) {
    int gi = i / 1056, r = i - gi * 1056;
    const float* grow = hcat + (size_t)(g0 + gi) * 512;
    float v = 0.f;
    if (r < 128)                  v = grow[r];
    else if (r >= 132 && r < 260) v = grow[128 + r - 132];
    else if (r >= 264 && r < 328) v = grow[256 + r - 264];
    else if (r >= 396) {
      int q = r - 396; int a = q / 132; int j = q - a * 132;
      if (j < 128)
        v = fmaxf(ahid[((size_t)(g0 + gi) * 5 + a) * 128 + j] + grow[320 + j], 0.f);
    }
    sbuf[i] = v;
  }
  __syncthreads();
  int gi = t >> 6, o = t & 63;
  int oc = o < 39 ? o : 39;
  int seg;
  if (oc < 4)       seg = 0;
  else if (oc < 8)  seg = 132;
  else if (oc == 8) seg = 264;
  else {
    int idx = (oc < 24) ? oc - 9 : oc - 24;
    seg = 396 + (idx / 3) * 132;
  }
  const float* ip = &sbuf[gi * 1056 + seg];
  float a0 = 0.f, a1 = 0.f, a2 = 0.f, a3 = 0.f;
#pragma unroll
  for (int j = 0; j < 128; j += 4) {
    a0 = fmaf(ip[j + 0], woutT[(j + 0) * 40 + oc], a0);
    a1 = fmaf(ip[j + 1], woutT[(j + 1) * 40 + oc], a1);
    a2 = fmaf(ip[j + 2], woutT[(j + 2) * 40 + oc], a2);
    a3 = fmaf(ip[j + 3], woutT[(j + 3) * 40 + oc], a3);
  }
  float res = (a0 + a1) + (a2 + a3) + bout[oc];
  if (o < 39) {
    if (o == 8)       res = 1.f / (1.f + __expf(-res));
    else if (o >= 24) res = 0.05f + 0.45f / (1.f + __expf(-res)) + 1e-6f;
    else if (o >= 9)  res = tanhf(res) * alim[(o - 9) % 3];
    out[(size_t)(g0 + gi) * 39 + o] = res;
  }
}

// ---------------------------------------------------------------------------
extern "C" void kernel_launch(void* const* d_in, const int* in_sizes, int n_in,
                              void* d_out, int out_size, void* d_ws, size_t ws_size,
                              hipStream_t stream) {
  const float* x     = (const float*)d_in[0];
  const float* eattr = (const float*)d_in[1];
  const float* W1  = (const float*)d_in[5];
  const float* as1 = (const float*)d_in[6];
  const float* ad1 = (const float*)d_in[7];
  const float* We1 = (const float*)d_in[8];
  const float* ae1 = (const float*)d_in[9];
  const float* b1  = (const float*)d_in[10];
  const float* W2  = (const float*)d_in[11];
  const float* as2 = (const float*)d_in[12];
  const float* ad2 = (const float*)d_in[13];
  const float* We2 = (const float*)d_in[14];
  const float* ae2 = (const float*)d_in[15];
  const float* b2  = (const float*)d_in[16];
  const float* pw1 = (const float*)d_in[17];
  const float* pb1 = (const float*)d_in[18];
  const float* pw2 = (const float*)d_in[19];
  const float* pb2 = (const float*)d_in[20];
  const float* qw1 = (const float*)d_in[21];
  const float* qb1 = (const float*)d_in[22];
  const float* qw2 = (const float*)d_in[23];
  const float* qb2 = (const float*)d_in[24];
  const float* aw1 = (const float*)d_in[25];
  const float* ab1 = (const float*)d_in[26];
  const float* aw2 = (const float*)d_in[27];
  const float* ab2 = (const float*)d_in[28];
  const float* tw1 = (const float*)d_in[29];
  const float* tb1 = (const float*)d_in[30];
  const float* tw2 = (const float*)d_in[31];
  const float* tb2 = (const float*)d_in[32];
  const float* alim = (const float*)d_in[33];

  const size_t BIGE = (size_t)NN * DD;
  char* p = (char*)d_ws;
  ushort_t* h2     = (ushort_t*)p; p += BIGE * 2;                // 42MB
  ushort_t* gmean  = (ushort_t*)p; p += (size_t)GG * DD * 2;     // 8.4MB
  ushort_t* xpad32 = (ushort_t*)p; p += (size_t)NN * 32 * 2;     // 2.6MB
  ushort_t* W1T32  = (ushort_t*)p; p += (size_t)512 * 32 * 2;
  ushort_t* W2T    = (ushort_t*)p; p += (size_t)512 * 512 * 2;
  ushort_t* WcatT  = (ushort_t*)p; p += (size_t)512 * 512 * 2;
  ushort_t* aw1topT = (ushort_t*)p; p += (size_t)128 * 512 * 2;
  ushort_t* wsc1T  = (ushort_t*)p; p += (size_t)16 * 32 * 2;
  ushort_t* wsc2T  = (ushort_t*)p; p += (size_t)16 * 512 * 2;
  float* bcat  = (float*)p; p += 512 * 4;
  float* sce   = (float*)p; p += 16 * 4;                          // [0,8)=L1 [8,16)=L2
  float* woutT = (float*)p; p += 5120 * 4;
  float* bout  = (float*)p; p += 40 * 4;
  float* ahid  = (float*)p; p += (size_t)NN * 128 * 4;            // 21MB
  float* hcat  = (float*)p;                                       // 16.8MB

  k_prep<<<1024 + 5120, 256, 0, stream>>>(
      x, W1, W2, pw1, qw1, tw1, aw1, pb1, qb1, tb1, ab1,
      We1, ae1, We2, ae2, as1, ad1, as2, ad2,
      pw2, pb2, qw2, qb2, tw2, tb2, aw2, ab2,
      xpad32, W1T32, W2T, WcatT, aw1topT, wsc1T, wsc2T,
      bcat, sce, woutT, bout);
  // --- both GAT layers fused; h1 never leaves LDS; barrier-free K-loop ---
  k_mega<<<GG / 16, 1024, 0, stream>>>(
      xpad32, W1T32, wsc1T, W2T, wsc2T, eattr, sce, b1, b2, h2, gmean);
  // --- heads (fused: ahid + hcat in one launch) ---
  k_hgemm<<<320 + 256, 256, 0, stream>>>(h2, aw1topT, ahid, gmean, WcatT, bcat, hcat);
  k_heads<<<GG / 4, 256, 0, stream>>>(hcat, ahid, woutT, bout, alim, (float*)d_out);
}

// Round 19
// 110.043 us; speedup vs baseline: 1.4684x; 1.4684x over previous
//
#include <hip/hip_runtime.h>
#include <hip/hip_bf16.h>
#include <math.h>

#define GG 8192
#define AA 5
#define NN (GG * AA)        // 40960
#define DD 512

typedef unsigned short ushort_t;
typedef unsigned int uint_t;

__device__ inline float bf2f(ushort_t u) {
  union { uint_t i; float f; } c; c.i = ((uint_t)u) << 16; return c.f;
}
__device__ inline ushort_t f2bf(float f) {
  union { float f; uint_t i; } c; c.f = f;
  uint_t r = c.i + 0x7fffu + ((c.i >> 16) & 1u);   // round-to-nearest-even
  return (ushort_t)(r >> 16);
}

using frag8 = __attribute__((ext_vector_type(8))) short;
using f32x4 = __attribute__((ext_vector_type(4))) float;

typedef __attribute__((address_space(3))) void lds_void;
typedef __attribute__((address_space(1))) const void gbl_void;
#define GLL(g, l) __builtin_amdgcn_global_load_lds((gbl_void*)(g), (lds_void*)(l), 16, 0, 0)

// XCD-chunked bijective swizzle (requires nwg % 8 == 0).
__device__ inline int xcd_swz(int bid, int nwg) {
  return (bid & 7) * (nwg >> 3) + (bid >> 3);
}

// ---------------------------------------------------------------------------
// Prep (grid = 1024 + 5120): weight packs + score-weight folds wsc = W @ a.
// wscT layout [16 score-col][K]; score-col s: head = s>>1, which = s&1
// (0 = a_s, 1 = a_d).
// ---------------------------------------------------------------------------
__global__ __launch_bounds__(256) void k_prep(
    const float* __restrict__ x, const float* __restrict__ W1,
    const float* __restrict__ W2, const float* __restrict__ pw1,
    const float* __restrict__ qw1, const float* __restrict__ tw1,
    const float* __restrict__ aw1, const float* __restrict__ pb1,
    const float* __restrict__ qb1, const float* __restrict__ tb1,
    const float* __restrict__ ab1, const float* __restrict__ We1,
    const float* __restrict__ ae1, const float* __restrict__ We2,
    const float* __restrict__ ae2, const float* __restrict__ as1,
    const float* __restrict__ ad1, const float* __restrict__ as2,
    const float* __restrict__ ad2, const float* __restrict__ pw2,
    const float* __restrict__ pb2, const float* __restrict__ qw2,
    const float* __restrict__ qb2, const float* __restrict__ tw2,
    const float* __restrict__ tb2, const float* __restrict__ aw2,
    const float* __restrict__ ab2, ushort_t* __restrict__ xpad32,
    ushort_t* __restrict__ W1T32, ushort_t* __restrict__ W2T,
    ushort_t* __restrict__ WcatT, ushort_t* __restrict__ aw1topT,
    ushort_t* __restrict__ wsc1T, ushort_t* __restrict__ wsc2T,
    float* __restrict__ bcat, float* __restrict__ sce,
    float* __restrict__ woutT, float* __restrict__ bout) {
  int b = blockIdx.x;
  int t = threadIdx.x;
  if (b < 1024) {
    int i = b * 256 + t;            // 0 .. 262143
    int n = i >> 9, k = i & 511;
    W2T[(size_t)n * 512 + k] = f2bf(W2[(size_t)k * 512 + n]);
    float v;
    if (n < 128)      v = pw1[(size_t)k * 128 + n];
    else if (n < 256) v = qw1[(size_t)k * 128 + (n - 128)];
    else if (n < 320) v = tw1[(size_t)k * 64 + (n - 256)];
    else if (n < 448) v = aw1[(size_t)(512 + k) * 128 + (n - 320)];
    else              v = 0.f;
    WcatT[(size_t)n * 512 + k] = f2bf(v);
    if (n < 128) aw1topT[(size_t)n * 512 + k] = f2bf(aw1[(size_t)k * 128 + n]);
    if (k == 0) {
      float bv;
      if (n < 128)      bv = pb1[n];
      else if (n < 256) bv = qb1[n - 128];
      else if (n < 320) bv = tb1[n - 256];
      else if (n < 448) bv = ab1[n - 320];
      else              bv = 0.f;
      bcat[n] = bv;
    }
    if (i < 512 * 32) {
      int nn = i >> 5, kk = i & 31;
      W1T32[i] = (kk < 29) ? f2bf(W1[(size_t)kk * 512 + nn]) : (ushort_t)0;
    }
    // wsc2T: [16][512]
    if (i < 8192) {
      int k2 = i & 511, s = i >> 9;
      int head = s >> 1;
      const float* av = ((s & 1) ? ad2 : as2) + head * 64;
      const float* wr = W2 + (size_t)k2 * 512 + head * 64;
      float val = 0.f;
      for (int c = 0; c < 64; ++c) val = fmaf(wr[c], av[c], val);
      wsc2T[i] = f2bf(val);
    }
    // wsc1T: [16][32]
    if (i < 512) {
      int k1 = i & 31, s = i >> 5;
      int head = s >> 1;
      float val = 0.f;
      if (k1 < 29) {
        const float* av = ((s & 1) ? ad1 : as1) + head * 64;
        const float* wr = W1 + (size_t)k1 * 512 + head * 64;
        for (int c = 0; c < 64; ++c) val = fmaf(wr[c], av[c], val);
      }
      wsc1T[i] = f2bf(val);
    }
    if (i < 16) {
      int h = i & 7;
      const float* Wp = (i < 8) ? We1 : We2;
      const float* ap = (i < 8) ? ae1 : ae2;
      float c = 0.f;
      for (int k2 = 0; k2 < 64; ++k2) c = fmaf(Wp[h * 64 + k2], ap[h * 64 + k2], c);
      sce[i] = c;
    }
    if (i < 5120) {
      int j = i / 40, o = i % 40;
      float wv;
      if (o < 4)       wv = pw2[j * 4 + o];
      else if (o < 8)  wv = qw2[j * 4 + (o - 4)];
      else if (o == 8) wv = (j < 64) ? tw2[j] : 0.f;
      else if (o < 24) wv = aw2[j * 6 + (o - 9) % 3];
      else if (o < 39) wv = aw2[j * 6 + 3 + (o - 24) % 3];
      else             wv = 0.f;
      woutT[i] = wv;
      if (j == 0) {
        float bv;
        if (o < 4)       bv = pb2[o];
        else if (o < 8)  bv = qb2[o - 4];
        else if (o == 8) bv = tb2[0];
        else if (o < 24) bv = ab2[(o - 9) % 3];
        else if (o < 39) bv = ab2[3 + (o - 24) % 3];
        else             bv = 0.f;
        bout[o] = bv;
      }
    }
  } else {
    int i = (b - 1024) * 256 + t;   // 0 .. 1310719
    int n = i >> 5, k = i & 31;
    xpad32[i] = (k < 29) ? f2bf(x[(size_t)n * 29 + k]) : (ushort_t)0;
  }
}

// ---------------------------------------------------------------------------
// MEGA-FUSED: both GAT layers for 16 graphs in one block; h1 never leaves LDS.
// 1024 threads = 16 waves; wave w owns cols [w*32, w*32+32) (2 n-tiles);
// wave 15 additionally computes the 16-col score tile (8 heads x {s,d}).
// Phase 1: L1 GEMM (single K-tile, GLL-staged) + scores + alpha + combine ->
//   h1 written INTO LDS in the XOR-swizzled A-fragment chunk layout.
// Phase 2: L2 GEMM streams W2T (+wsc2T), T3-MINIMUM schedule: one barrier
//   per iteration {STAGE(next) -> ds_read -> MFMA -> vmcnt(0) -> barrier}.
//   End-of-iter barrier proves both "my stage landed" and "all waves done
//   reading the buffer the next STAGE overwrites". 16 barriers (was 32).
// LDS map: h1buf @0 (81920); B2 dbuf @81920/114688 (32768 ea); P1: W1T32
//   @81920, A1 @114688, S1 @119808; epilogues: Hbf @81920 (42240), sal
//   @124160, sss @136960, ssd @139520; S2 dbuf @147456 (2x1024).
// ---------------------------------------------------------------------------
__global__ __launch_bounds__(1024) void k_mega(
    const ushort_t* __restrict__ xpad32, const ushort_t* __restrict__ W1T32,
    const ushort_t* __restrict__ wsc1T, const ushort_t* __restrict__ W2T,
    const ushort_t* __restrict__ wsc2T, const float* __restrict__ eattr,
    const float* __restrict__ sce, const float* __restrict__ b1,
    const float* __restrict__ b2, ushort_t* __restrict__ h2,
    ushort_t* __restrict__ gmean) {
  __shared__ __align__(16) char smem[149504];
  const int t = threadIdx.x;
  const int lane = t & 63;
  const int w = t >> 6;                   // 0..15
  const int l15 = lane & 15;
  const int ko2 = ((((lane >> 4) ^ (lane & 3) ^ ((lane >> 2) & 3)) & 3) * 16);
  int lid = xcd_swz(blockIdx.x, gridDim.x);
  const int m0 = lid * 80;
  const int g0 = lid * 16;
  ushort_t* h1buf = (ushort_t*)smem;
  float* sal = (float*)(smem + 124160);   // [80 dst(gi*5+j)][5 src][8 hd]
  float* sss = (float*)(smem + 136960);   // [80][8]
  float* ssd = (float*)(smem + 139520);   // [80][8]
  const f32x4 zz = {0.f, 0.f, 0.f, 0.f};
  f32x4 acc[5][2], asc[5];
#pragma unroll
  for (int mt = 0; mt < 5; ++mt) { acc[mt][0] = zz; acc[mt][1] = zz; asc[mt] = zz; }

  // ================= PHASE 1: layer-1 GEMM (single K-tile) ==================
  {
#pragma unroll
    for (int r_ = 0; r_ < 2; ++r_) {
      int c_ = t + r_ * 1024; int row_ = c_ >> 2;
      int sw_ = ((((c_ & 3) ^ (row_ & 3) ^ ((row_ >> 2) & 3)) & 3)) * 8;
      GLL(W1T32 + (size_t)row_ * 32 + sw_, smem + 81920 + c_ * 16);
    }
    if (t < 320) {
      int c_ = t; int row_ = c_ >> 2;
      int sw_ = ((((c_ & 3) ^ (row_ & 3) ^ ((row_ >> 2) & 3)) & 3)) * 8;
      GLL(xpad32 + (size_t)(m0 + row_) * 32 + sw_, smem + 114688 + c_ * 16);
    } else if (t < 384) {
      int c_ = t - 320; int row_ = c_ >> 2;
      int sw_ = ((((c_ & 3) ^ (row_ & 3) ^ ((row_ >> 2) & 3)) & 3)) * 8;
      GLL(wsc1T + (size_t)row_ * 32 + sw_, smem + 119808 + c_ * 16);
    }
  }
  asm volatile("s_waitcnt vmcnt(0)" ::: "memory");
  __builtin_amdgcn_s_barrier();
  {
    const char* bb = smem + 81920;
    const char* aa = smem + 114688;
    const char* sb = smem + 119808;
    frag8 af[5], bfr[2];
#pragma unroll
    for (int mt = 0; mt < 5; ++mt)
      af[mt] = *(const frag8*)(aa + (mt * 16 + l15) * 64 + ko2);
#pragma unroll
    for (int n = 0; n < 2; ++n)
      bfr[n] = *(const frag8*)(bb + ((2 * w + n) * 16 + l15) * 64 + ko2);
#pragma unroll
    for (int mt = 0; mt < 5; ++mt)
#pragma unroll
      for (int n = 0; n < 2; ++n)
        acc[mt][n] = __builtin_amdgcn_mfma_f32_16x16x32_bf16(af[mt], bfr[n], acc[mt][n], 0, 0, 0);
    if (w == 15) {
      frag8 sfr = *(const frag8*)(sb + l15 * 64 + ko2);
#pragma unroll
      for (int mt = 0; mt < 5; ++mt)
        asc[mt] = __builtin_amdgcn_mfma_f32_16x16x32_bf16(af[mt], sfr, asc[mt], 0, 0, 0);
    }
  }
  if (w == 15) {
    float* dst = (l15 & 1) ? ssd : sss;
    int hd = l15 >> 1;
    int q4 = (lane >> 4) * 4;
#pragma unroll
    for (int mt = 0; mt < 5; ++mt)
#pragma unroll
      for (int r = 0; r < 4; ++r)
        dst[(mt * 16 + q4 + r) * 8 + hd] = asc[mt][r];
  }
  __syncthreads();
  // alpha-1: 640 units (gi, dst j, hd)
  if (t < 640) {
    int gi = t / 40, jh = t % 40;
    int j = jh >> 3, hd = jh & 7;
    int g = g0 + gi;
    float sdj = ssd[(gi * 5 + j) * 8 + hd];
    float ce = sce[hd];
    float lg[5], mx = -1e30f;
#pragma unroll
    for (int i = 0; i < 5; ++i) {
      float l = sss[(gi * 5 + i) * 8 + hd] + sdj;
      if (i != j) l = fmaf(eattr[(size_t)g * 20 + i * 4 + (j > i ? j - 1 : j)], ce, l);
      l = l > 0.f ? l : 0.2f * l;      // leaky_relu(0.2)
      lg[i] = l; mx = fmaxf(mx, l);
    }
    float s = 0.f;
#pragma unroll
    for (int i = 0; i < 5; ++i) { lg[i] = __expf(lg[i] - mx); s += lg[i]; }
    float inv = 1.f / (s + 1e-16f);
#pragma unroll
    for (int i = 0; i < 5; ++i) sal[((gi * 5 + j) * 5 + i) * 8 + hd] = lg[i] * inv;
  }
  __syncthreads();
  // epilogue-1: 4 passes of 128 cols; combine -> h1buf (LDS, swizzled chunks)
  {
    float* hbf = (float*)(smem + 81920);   // [80][132]
#pragma unroll
    for (int p = 0; p < 4; ++p) {
      if ((w >> 2) == p) {
        int q4 = (lane >> 4) * 4;
#pragma unroll
        for (int mt = 0; mt < 5; ++mt)
#pragma unroll
          for (int n = 0; n < 2; ++n) {
            int lc = (w & 3) * 32 + n * 16 + l15;
#pragma unroll
            for (int r = 0; r < 4; ++r)
              hbf[(mt * 16 + q4 + r) * 132 + lc] = acc[mt][n][r];
          }
      }
      __syncthreads();
      if (t < 512) {
        int gi = t >> 5, cq = t & 31;
        int hd = 2 * p + (cq >> 4);
        int cg = p * 128 + cq * 4;
        float hv[5][4];
#pragma unroll
        for (int i = 0; i < 5; ++i)
          *(float4*)hv[i] = *(const float4*)&hbf[(gi * 5 + i) * 132 + cq * 4];
        float4 bb4 = *(const float4*)&b1[cg];
        int chunk = cg >> 5, slot = (cg >> 3) & 3, boff = (cg & 7) * 2;
#pragma unroll
        for (int j = 0; j < 5; ++j) {
          float o0 = bb4.x, o1 = bb4.y, o2 = bb4.z, o3 = bb4.w;
#pragma unroll
          for (int i = 0; i < 5; ++i) {
            float a = sal[((gi * 5 + j) * 5 + i) * 8 + hd];
            o0 = fmaf(a, hv[i][0], o0); o1 = fmaf(a, hv[i][1], o1);
            o2 = fmaf(a, hv[i][2], o2); o3 = fmaf(a, hv[i][3], o3);
          }
          o0 = fmaxf(o0, 0.f); o1 = fmaxf(o1, 0.f);
          o2 = fmaxf(o2, 0.f); o3 = fmaxf(o3, 0.f);
          uint2 wv_;
          wv_.x = (uint_t)f2bf(o0) | ((uint_t)f2bf(o1) << 16);
          wv_.y = (uint_t)f2bf(o2) | ((uint_t)f2bf(o3) << 16);
          int row = gi * 5 + j;
          int phys = slot ^ (row & 3) ^ ((row >> 2) & 3);
          *(uint2*)((char*)h1buf + chunk * 5120 + row * 64 + phys * 16 + boff) = wv_;
        }
      }
      __syncthreads();
    }
  }

  // ========= PHASE 2: layer-2 GEMM (K=512), T3-minimum single barrier ======
#pragma unroll
  for (int mt = 0; mt < 5; ++mt) { acc[mt][0] = zz; acc[mt][1] = zz; asc[mt] = zz; }
#define FS2(bi, kk0)                                                           \
  {                                                                            \
    char* bb_ = smem + 81920 + (bi) * 32768;                                   \
    char* sb_ = smem + 147456 + (bi) * 1024;                                   \
    _Pragma("unroll")                                                          \
    for (int r_ = 0; r_ < 2; ++r_) {                                           \
      int c_ = t + r_ * 1024; int row_ = c_ >> 2;                              \
      int sw_ = ((((c_ & 3) ^ (row_ & 3) ^ ((row_ >> 2) & 3)) & 3)) * 8;       \
      GLL(W2T + (size_t)row_ * 512 + (kk0) + sw_, bb_ + c_ * 16);              \
    }                                                                          \
    if (t < 64) {                                                              \
      int c_ = t; int row_ = c_ >> 2;                                          \
      int sw_ = ((((c_ & 3) ^ (row_ & 3) ^ ((row_ >> 2) & 3)) & 3)) * 8;       \
      GLL(wsc2T + (size_t)row_ * 512 + (kk0) + sw_, sb_ + c_ * 16);            \
    }                                                                          \
  }
  FS2(0, 0);
  asm volatile("s_waitcnt vmcnt(0)" ::: "memory");
  __builtin_amdgcn_s_barrier();
  for (int ts = 0; ts < 16; ++ts) {
    int cur = ts & 1;
    // issue next stage into the buffer read two iterations ago (safe: the
    // end-of-previous-iteration barrier proves all waves finished it).
    if (ts + 1 < 16) FS2(cur ^ 1, (ts + 1) * 32);
    const char* bb = smem + 81920 + cur * 32768;
    const char* aa = (const char*)h1buf + ts * 5120;
    const char* sb = smem + 147456 + cur * 1024;
    frag8 af[5], bfr[2];
#pragma unroll
    for (int mt = 0; mt < 5; ++mt)
      af[mt] = *(const frag8*)(aa + (mt * 16 + l15) * 64 + ko2);
#pragma unroll
    for (int n = 0; n < 2; ++n)
      bfr[n] = *(const frag8*)(bb + ((2 * w + n) * 16 + l15) * 64 + ko2);
    __builtin_amdgcn_s_setprio(1);
#pragma unroll
    for (int mt = 0; mt < 5; ++mt)
#pragma unroll
      for (int n = 0; n < 2; ++n)
        acc[mt][n] = __builtin_amdgcn_mfma_f32_16x16x32_bf16(af[mt], bfr[n], acc[mt][n], 0, 0, 0);
    if (w == 15) {
      frag8 sfr = *(const frag8*)(sb + l15 * 64 + ko2);
#pragma unroll
      for (int mt = 0; mt < 5; ++mt)
        asc[mt] = __builtin_amdgcn_mfma_f32_16x16x32_bf16(af[mt], sfr, asc[mt], 0, 0, 0);
    }
    __builtin_amdgcn_s_setprio(0);
    __builtin_amdgcn_sched_barrier(0);
    asm volatile("s_waitcnt vmcnt(0)" ::: "memory");
    __builtin_amdgcn_s_barrier();
  }
#undef FS2
  // scores spill (staging bufs dead after final barrier)
  if (w == 15) {
    float* dst = (l15 & 1) ? ssd : sss;
    int hd = l15 >> 1;
    int q4 = (lane >> 4) * 4;
#pragma unroll
    for (int mt = 0; mt < 5; ++mt)
#pragma unroll
      for (int r = 0; r < 4; ++r)
        dst[(mt * 16 + q4 + r) * 8 + hd] = asc[mt][r];
  }
  __syncthreads();
  // alpha-2
  if (t < 640) {
    int gi = t / 40, jh = t % 40;
    int j = jh >> 3, hd = jh & 7;
    int g = g0 + gi;
    float sdj = ssd[(gi * 5 + j) * 8 + hd];
    float ce = sce[8 + hd];
    float lg[5], mx = -1e30f;
#pragma unroll
    for (int i = 0; i < 5; ++i) {
      float l = sss[(gi * 5 + i) * 8 + hd] + sdj;
      if (i != j) l = fmaf(eattr[(size_t)g * 20 + i * 4 + (j > i ? j - 1 : j)], ce, l);
      l = l > 0.f ? l : 0.2f * l;
      lg[i] = l; mx = fmaxf(mx, l);
    }
    float s = 0.f;
#pragma unroll
    for (int i = 0; i < 5; ++i) { lg[i] = __expf(lg[i] - mx); s += lg[i]; }
    float inv = 1.f / (s + 1e-16f);
#pragma unroll
    for (int i = 0; i < 5; ++i) sal[((gi * 5 + j) * 5 + i) * 8 + hd] = lg[i] * inv;
  }
  __syncthreads();
  // epilogue-2: 4 passes of 128 cols; combine -> h2 + gmean (global)
  {
    float* hbf = (float*)(smem + 81920);   // [80][132]
#pragma unroll
    for (int p = 0; p < 4; ++p) {
      if ((w >> 2) == p) {
        int q4 = (lane >> 4) * 4;
#pragma unroll
        for (int mt = 0; mt < 5; ++mt)
#pragma unroll
          for (int n = 0; n < 2; ++n) {
            int lc = (w & 3) * 32 + n * 16 + l15;
#pragma unroll
            for (int r = 0; r < 4; ++r)
              hbf[(mt * 16 + q4 + r) * 132 + lc] = acc[mt][n][r];
          }
      }
      __syncthreads();
      if (t < 512) {
        int gi = t >> 5, cq = t & 31;
        int hd = 2 * p + (cq >> 4);
        int cg = p * 128 + cq * 4;
        float hv[5][4];
#pragma unroll
        for (int i = 0; i < 5; ++i)
          *(float4*)hv[i] = *(const float4*)&hbf[(gi * 5 + i) * 132 + cq * 4];
        float4 bb4 = *(const float4*)&b2[cg];
        float gs0 = 0.f, gs1 = 0.f, gs2 = 0.f, gs3 = 0.f;
#pragma unroll
        for (int j = 0; j < 5; ++j) {
          float o0 = bb4.x, o1 = bb4.y, o2 = bb4.z, o3 = bb4.w;
#pragma unroll
          for (int i = 0; i < 5; ++i) {
            float a = sal[((gi * 5 + j) * 5 + i) * 8 + hd];
            o0 = fmaf(a, hv[i][0], o0); o1 = fmaf(a, hv[i][1], o1);
            o2 = fmaf(a, hv[i][2], o2); o3 = fmaf(a, hv[i][3], o3);
          }
          o0 = fmaxf(o0, 0.f); o1 = fmaxf(o1, 0.f);
          o2 = fmaxf(o2, 0.f); o3 = fmaxf(o3, 0.f);
          uint2 wv_;
          wv_.x = (uint_t)f2bf(o0) | ((uint_t)f2bf(o1) << 16);
          wv_.y = (uint_t)f2bf(o2) | ((uint_t)f2bf(o3) << 16);
          *(uint2*)(h2 + ((size_t)(g0 + gi) * 5 + j) * 512 + cg) = wv_;
          gs0 += o0; gs1 += o1; gs2 += o2; gs3 += o3;
        }
        uint2 wv_;
        wv_.x = (uint_t)f2bf(gs0 * 0.2f) | ((uint_t)f2bf(gs1 * 0.2f) << 16);
        wv_.y = (uint_t)f2bf(gs2 * 0.2f) | ((uint_t)f2bf(gs3 * 0.2f) << 16);
        *(uint2*)(gmean + (size_t)(g0 + gi) * 512 + cg) = wv_;
      }
      __syncthreads();
    }
  }
}

// ---------------------------------------------------------------------------
// bf16 MFMA GEMM body — unchanged; used by the head GEMMs.
// EPI: 1 = f32 out; 2 = f32 out + bias + relu(col<320)
// ---------------------------------------------------------------------------
template <int EPI>
__device__ __forceinline__ void gemm_body(
    const ushort_t* __restrict__ A, const ushort_t* __restrict__ BT,
    const float* __restrict__ bias, void* __restrict__ Cv,
    int M, int N, int K, int m0, int n0, char* lds) {
  int t = threadIdx.x;
  int lane = t & 63;
  int wv = t >> 6;
  int wr = (wv >> 1) * 64, wc = (wv & 1) * 64;
  f32x4 acc[4][4] = {};
  int ch0 = t, ch1 = t + 256;
  int row0 = ch0 >> 2, row1 = ch1 >> 2;
  int sw0 = (((ch0 & 3) ^ (row0 & 3) ^ ((row0 >> 2) & 3)) & 3) * 8;
  int sw1 = (((ch1 & 3) ^ (row1 & 3) ^ ((row1 >> 2) & 3)) & 3) * 8;
  int ko2 = ((((lane >> 4) ^ (lane & 3) ^ ((lane >> 2) & 3)) & 3) * 16);
  const int nt = K >> 5;
#define STAGE(bi, kk0)                                                         \
  {                                                                            \
    char* ab = lds + (bi) * 16384;                                             \
    GLL(A + (size_t)(m0 + row0) * K + (kk0) + sw0, ab + ch0 * 16);             \
    GLL(A + (size_t)(m0 + row1) * K + (kk0) + sw1, ab + ch1 * 16);             \
    GLL(BT + (size_t)(n0 + row0) * K + (kk0) + sw0, ab + 8192 + ch0 * 16);     \
    GLL(BT + (size_t)(n0 + row1) * K + (kk0) + sw1, ab + 8192 + ch1 * 16);     \
  }
  STAGE(0, 0);
  if (nt > 1) STAGE(1, 32);
  for (int ts = 0; ts < nt; ++ts) {
    int bi = ts % 3;
    if (ts + 2 < nt) {
      STAGE((ts + 2) % 3, (ts + 2) * 32);
      asm volatile("s_waitcnt vmcnt(8)" ::: "memory");
    } else if (ts + 1 < nt) {
      asm volatile("s_waitcnt vmcnt(4)" ::: "memory");
    } else {
      asm volatile("s_waitcnt vmcnt(0)" ::: "memory");
    }
    __builtin_amdgcn_s_barrier();
    __builtin_amdgcn_sched_barrier(0);
    const char* ab = lds + bi * 16384;
    frag8 af[4], bfr[4];
#pragma unroll
    for (int m = 0; m < 4; ++m)
      af[m] = *(const frag8*)(ab + (wr + m * 16 + (lane & 15)) * 64 + ko2);
#pragma unroll
    for (int n = 0; n < 4; ++n)
      bfr[n] = *(const frag8*)(ab + 8192 + (wc + n * 16 + (lane & 15)) * 64 + ko2);
#pragma unroll
    for (int m = 0; m < 4; ++m)
#pragma unroll
      for (int n = 0; n < 4; ++n)
        acc[m][n] = __builtin_amdgcn_mfma_f32_16x16x32_bf16(af[m], bfr[n], acc[m][n], 0, 0, 0);
    __builtin_amdgcn_sched_barrier(0);
    __builtin_amdgcn_s_barrier();
  }
#undef STAGE
  int r4 = (lane >> 4) * 4;
  int cl = lane & 15;
#pragma unroll
  for (int m = 0; m < 4; ++m) {
#pragma unroll
    for (int n = 0; n < 4; ++n) {
      int col = n0 + wc + n * 16 + cl;
      float bb = (EPI == 2) ? bias[col] : 0.f;
#pragma unroll
      for (int r = 0; r < 4; ++r) {
        int row = m0 + wr + m * 16 + r4 + r;
        float v = acc[m][n][r] + bb;
        if (EPI == 2 && col < 320) v = fmaxf(v, 0.f);
        ((float*)Cv)[(size_t)row * N + col] = v;
      }
    }
  }
}

// Fused head GEMMs: blocks [0,320) -> ahid = h2 @ aw1topT^T (f32 out);
// blocks [320,576) -> hcat = gmean @ WcatT^T + bcat, relu(col<320).
__global__ __launch_bounds__(256) void k_hgemm(
    const ushort_t* __restrict__ h2, const ushort_t* __restrict__ aw1topT,
    float* __restrict__ ahid, const ushort_t* __restrict__ gmean,
    const ushort_t* __restrict__ WcatT, const float* __restrict__ bcat,
    float* __restrict__ hcat) {
  __shared__ char lds[49152];
  int bid = blockIdx.x;
  if (bid < 320) {
    int lid = xcd_swz(bid, 320);
    gemm_body<1>(h2, aw1topT, nullptr, ahid, NN, 128, DD, lid * 128, 0, lds);
  } else {
    int lid = xcd_swz(bid - 320, 256);
    gemm_body<2>(gmean, WcatT, bcat, hcat, GG, DD, DD, (lid >> 2) * 128, (lid & 3) * 128, lds);
  }
}

// ---------------------------------------------------------------------------
// Final heads — unchanged.
// ---------------------------------------------------------------------------
__global__ __launch_bounds__(256) void k_heads(
    const float* __restrict__ hcat, const float* __restrict__ ahid,
    const float* __restrict__ woutT, const float* __restrict__ bout,
    const float* __restrict__ alim, float* __restrict__ out) {
  int g0 = blockIdx.x * 4;
  int t = threadIdx.x;
  __shared__ float sbuf[4224];
  for (int i = t; i < 4224; i += 256) {
    int gi = i / 1056, r = i - gi * 1056;
    const float* grow = hcat + (size_t)(g0 + gi) * 512;
    float v = 0.f;
    if (r < 128)                  v = grow[r];
    else if (r >= 132 && r < 260) v = grow[128 + r - 132];
    else if (r >= 264 && r < 328) v = grow[256 + r - 264];
    else if (r >= 396) {
      int q = r - 396; int a = q / 132; int j = q - a * 132;
      if (j < 128)
        v = fmaxf(ahid[((size_t)(g0 + gi) * 5 + a) * 128 + j] + grow[320 + j], 0.f);
    }
    sbuf[i] = v;
  }
  __syncthreads();
  int gi = t >> 6, o = t & 63;
  int oc = o < 39 ? o : 39;
  int seg;
  if (oc < 4)       seg = 0;
  else if (oc < 8)  seg = 132;
  else if (oc == 8) seg = 264;
  else {
    int idx = (oc < 24) ? oc - 9 : oc - 24;
    seg = 396 + (idx / 3) * 132;
  }
  const float* ip = &sbuf[gi * 1056 + seg];
  float a0 = 0.f, a1 = 0.f, a2 = 0.f, a3 = 0.f;
#pragma unroll
  for (int j = 0; j < 128; j += 4) {
    a0 = fmaf(ip[j + 0], woutT[(j + 0) * 40 + oc], a0);
    a1 = fmaf(ip[j + 1], woutT[(j + 1) * 40 + oc], a1);
    a2 = fmaf(ip[j + 2], woutT[(j + 2) * 40 + oc], a2);
    a3 = fmaf(ip[j + 3], woutT[(j + 3) * 40 + oc], a3);
  }
  float res = (a0 + a1) + (a2 + a3) + bout[oc];
  if (o < 39) {
    if (o == 8)       res = 1.f / (1.f + __expf(-res));
    else if (o >= 24) res = 0.05f + 0.45f / (1.f + __expf(-res)) + 1e-6f;
    else if (o >= 9)  res = tanhf(res) * alim[(o - 9) % 3];
    out[(size_t)(g0 + gi) * 39 + o] = res;
  }
}

// ---------------------------------------------------------------------------
extern "C" void kernel_launch(void* const* d_in, const int* in_sizes, int n_in,
                              void* d_out, int out_size, void* d_ws, size_t ws_size,
                              hipStream_t stream) {
  const float* x     = (const float*)d_in[0];
  const float* eattr = (const float*)d_in[1];
  const float* W1  = (const float*)d_in[5];
  const float* as1 = (const float*)d_in[6];
  const float* ad1 = (const float*)d_in[7];
  const float* We1 = (const float*)d_in[8];
  const float* ae1 = (const float*)d_in[9];
  const float* b1  = (const float*)d_in[10];
  const float* W2  = (const float*)d_in[11];
  const float* as2 = (const float*)d_in[12];
  const float* ad2 = (const float*)d_in[13];
  const float* We2 = (const float*)d_in[14];
  const float* ae2 = (const float*)d_in[15];
  const float* b2  = (const float*)d_in[16];
  const float* pw1 = (const float*)d_in[17];
  const float* pb1 = (const float*)d_in[18];
  const float* pw2 = (const float*)d_in[19];
  const float* pb2 = (const float*)d_in[20];
  const float* qw1 = (const float*)d_in[21];
  const float* qb1 = (const float*)d_in[22];
  const float* qw2 = (const float*)d_in[23];
  const float* qb2 = (const float*)d_in[24];
  const float* aw1 = (const float*)d_in[25];
  const float* ab1 = (const float*)d_in[26];
  const float* aw2 = (const float*)d_in[27];
  const float* ab2 = (const float*)d_in[28];
  const float* tw1 = (const float*)d_in[29];
  const float* tb1 = (const float*)d_in[30];
  const float* tw2 = (const float*)d_in[31];
  const float* tb2 = (const float*)d_in[32];
  const float* alim = (const float*)d_in[33];

  const size_t BIGE = (size_t)NN * DD;
  char* p = (char*)d_ws;
  ushort_t* h2     = (ushort_t*)p; p += BIGE * 2;                // 42MB
  ushort_t* gmean  = (ushort_t*)p; p += (size_t)GG * DD * 2;     // 8.4MB
  ushort_t* xpad32 = (ushort_t*)p; p += (size_t)NN * 32 * 2;     // 2.6MB
  ushort_t* W1T32  = (ushort_t*)p; p += (size_t)512 * 32 * 2;
  ushort_t* W2T    = (ushort_t*)p; p += (size_t)512 * 512 * 2;
  ushort_t* WcatT  = (ushort_t*)p; p += (size_t)512 * 512 * 2;
  ushort_t* aw1topT = (ushort_t*)p; p += (size_t)128 * 512 * 2;
  ushort_t* wsc1T  = (ushort_t*)p; p += (size_t)16 * 32 * 2;
  ushort_t* wsc2T  = (ushort_t*)p; p += (size_t)16 * 512 * 2;
  float* bcat  = (float*)p; p += 512 * 4;
  float* sce   = (float*)p; p += 16 * 4;                          // [0,8)=L1 [8,16)=L2
  float* woutT = (float*)p; p += 5120 * 4;
  float* bout  = (float*)p; p += 40 * 4;
  float* ahid  = (float*)p; p += (size_t)NN * 128 * 4;            // 21MB
  float* hcat  = (float*)p;                                       // 16.8MB

  k_prep<<<1024 + 5120, 256, 0, stream>>>(
      x, W1, W2, pw1, qw1, tw1, aw1, pb1, qb1, tb1, ab1,
      We1, ae1, We2, ae2, as1, ad1, as2, ad2,
      pw2, pb2, qw2, qb2, tw2, tb2, aw2, ab2,
      xpad32, W1T32, W2T, WcatT, aw1topT, wsc1T, wsc2T,
      bcat, sce, woutT, bout);
  // --- both GAT layers fused; h1 never leaves LDS ---
  k_mega<<<GG / 16, 1024, 0, stream>>>(
      xpad32, W1T32, wsc1T, W2T, wsc2T, eattr, sce, b1, b2, h2, gmean);
  // --- heads (fused: ahid + hcat in one launch) ---
  k_hgemm<<<320 + 256, 256, 0, stream>>>(h2, aw1topT, ahid, gmean, WcatT, bcat, hcat);
  k_heads<<<GG / 4, 256, 0, stream>>>(hcat, ahid, woutT, bout, alim, (float*)d_out);
}

// Round 20
// 105.703 us; speedup vs baseline: 1.5287x; 1.0411x over previous
//
#include <hip/hip_runtime.h>
#include <hip/hip_bf16.h>
#include <math.h>

#define GG 8192
#define AA 5
#define NN (GG * AA)        // 40960
#define DD 512

typedef unsigned short ushort_t;
typedef unsigned int uint_t;

__device__ inline float bf2f(ushort_t u) {
  union { uint_t i; float f; } c; c.i = ((uint_t)u) << 16; return c.f;
}
__device__ inline ushort_t f2bf(float f) {
  union { float f; uint_t i; } c; c.f = f;
  uint_t r = c.i + 0x7fffu + ((c.i >> 16) & 1u);   // round-to-nearest-even
  return (ushort_t)(r >> 16);
}

using frag8 = __attribute__((ext_vector_type(8))) short;
using f32x4 = __attribute__((ext_vector_type(4))) float;

typedef __attribute__((address_space(3))) void lds_void;
typedef __attribute__((address_space(1))) const void gbl_void;
#define GLL(g, l) __builtin_amdgcn_global_load_lds((gbl_void*)(g), (lds_void*)(l), 16, 0, 0)

// XCD-chunked bijective swizzle (requires nwg % 8 == 0).
__device__ inline int xcd_swz(int bid, int nwg) {
  return (bid & 7) * (nwg >> 3) + (bid >> 3);
}

// ---------------------------------------------------------------------------
// Prep — unchanged from round 19.
// ---------------------------------------------------------------------------
__global__ __launch_bounds__(256) void k_prep(
    const float* __restrict__ x, const float* __restrict__ W1,
    const float* __restrict__ W2, const float* __restrict__ pw1,
    const float* __restrict__ qw1, const float* __restrict__ tw1,
    const float* __restrict__ aw1, const float* __restrict__ pb1,
    const float* __restrict__ qb1, const float* __restrict__ tb1,
    const float* __restrict__ ab1, const float* __restrict__ We1,
    const float* __restrict__ ae1, const float* __restrict__ We2,
    const float* __restrict__ ae2, const float* __restrict__ as1,
    const float* __restrict__ ad1, const float* __restrict__ as2,
    const float* __restrict__ ad2, const float* __restrict__ pw2,
    const float* __restrict__ pb2, const float* __restrict__ qw2,
    const float* __restrict__ qb2, const float* __restrict__ tw2,
    const float* __restrict__ tb2, const float* __restrict__ aw2,
    const float* __restrict__ ab2, ushort_t* __restrict__ xpad32,
    ushort_t* __restrict__ W1T32, ushort_t* __restrict__ W2T,
    ushort_t* __restrict__ WcatT, ushort_t* __restrict__ aw1topT,
    ushort_t* __restrict__ wsc1T, ushort_t* __restrict__ wsc2T,
    float* __restrict__ bcat, float* __restrict__ sce,
    float* __restrict__ woutT, float* __restrict__ bout) {
  int b = blockIdx.x;
  int t = threadIdx.x;
  if (b < 1024) {
    int i = b * 256 + t;            // 0 .. 262143
    int n = i >> 9, k = i & 511;
    W2T[(size_t)n * 512 + k] = f2bf(W2[(size_t)k * 512 + n]);
    float v;
    if (n < 128)      v = pw1[(size_t)k * 128 + n];
    else if (n < 256) v = qw1[(size_t)k * 128 + (n - 128)];
    else if (n < 320) v = tw1[(size_t)k * 64 + (n - 256)];
    else if (n < 448) v = aw1[(size_t)(512 + k) * 128 + (n - 320)];
    else              v = 0.f;
    WcatT[(size_t)n * 512 + k] = f2bf(v);
    if (n < 128) aw1topT[(size_t)n * 512 + k] = f2bf(aw1[(size_t)k * 128 + n]);
    if (k == 0) {
      float bv;
      if (n < 128)      bv = pb1[n];
      else if (n < 256) bv = qb1[n - 128];
      else if (n < 320) bv = tb1[n - 256];
      else if (n < 448) bv = ab1[n - 320];
      else              bv = 0.f;
      bcat[n] = bv;
    }
    if (i < 512 * 32) {
      int nn = i >> 5, kk = i & 31;
      W1T32[i] = (kk < 29) ? f2bf(W1[(size_t)kk * 512 + nn]) : (ushort_t)0;
    }
    // wsc2T: [16][512]
    if (i < 8192) {
      int k2 = i & 511, s = i >> 9;
      int head = s >> 1;
      const float* av = ((s & 1) ? ad2 : as2) + head * 64;
      const float* wr = W2 + (size_t)k2 * 512 + head * 64;
      float val = 0.f;
      for (int c = 0; c < 64; ++c) val = fmaf(wr[c], av[c], val);
      wsc2T[i] = f2bf(val);
    }
    // wsc1T: [16][32]
    if (i < 512) {
      int k1 = i & 31, s = i >> 5;
      int head = s >> 1;
      float val = 0.f;
      if (k1 < 29) {
        const float* av = ((s & 1) ? ad1 : as1) + head * 64;
        const float* wr = W1 + (size_t)k1 * 512 + head * 64;
        for (int c = 0; c < 64; ++c) val = fmaf(wr[c], av[c], val);
      }
      wsc1T[i] = f2bf(val);
    }
    if (i < 16) {
      int h = i & 7;
      const float* Wp = (i < 8) ? We1 : We2;
      const float* ap = (i < 8) ? ae1 : ae2;
      float c = 0.f;
      for (int k2 = 0; k2 < 64; ++k2) c = fmaf(Wp[h * 64 + k2], ap[h * 64 + k2], c);
      sce[i] = c;
    }
    if (i < 5120) {
      int j = i / 40, o = i % 40;
      float wv;
      if (o < 4)       wv = pw2[j * 4 + o];
      else if (o < 8)  wv = qw2[j * 4 + (o - 4)];
      else if (o == 8) wv = (j < 64) ? tw2[j] : 0.f;
      else if (o < 24) wv = aw2[j * 6 + (o - 9) % 3];
      else if (o < 39) wv = aw2[j * 6 + 3 + (o - 24) % 3];
      else             wv = 0.f;
      woutT[i] = wv;
      if (j == 0) {
        float bv;
        if (o < 4)       bv = pb2[o];
        else if (o < 8)  bv = qb2[o - 4];
        else if (o == 8) bv = tb2[0];
        else if (o < 24) bv = ab2[(o - 9) % 3];
        else if (o < 39) bv = ab2[3 + (o - 24) % 3];
        else             bv = 0.f;
        bout[o] = bv;
      }
    }
  } else {
    int i = (b - 1024) * 256 + t;   // 0 .. 1310719
    int n = i >> 5, k = i & 31;
    xpad32[i] = (k < 29) ? f2bf(x[(size_t)n * 29 + k]) : (ushort_t)0;
  }
}

// ---------------------------------------------------------------------------
// MEGA-FUSED — unchanged from round 19 (best measured).
// ---------------------------------------------------------------------------
__global__ __launch_bounds__(1024) void k_mega(
    const ushort_t* __restrict__ xpad32, const ushort_t* __restrict__ W1T32,
    const ushort_t* __restrict__ wsc1T, const ushort_t* __restrict__ W2T,
    const ushort_t* __restrict__ wsc2T, const float* __restrict__ eattr,
    const float* __restrict__ sce, const float* __restrict__ b1,
    const float* __restrict__ b2, ushort_t* __restrict__ h2,
    ushort_t* __restrict__ gmean) {
  __shared__ __align__(16) char smem[149504];
  const int t = threadIdx.x;
  const int lane = t & 63;
  const int w = t >> 6;                   // 0..15
  const int l15 = lane & 15;
  const int ko2 = ((((lane >> 4) ^ (lane & 3) ^ ((lane >> 2) & 3)) & 3) * 16);
  int lid = xcd_swz(blockIdx.x, gridDim.x);
  const int m0 = lid * 80;
  const int g0 = lid * 16;
  ushort_t* h1buf = (ushort_t*)smem;
  float* sal = (float*)(smem + 124160);   // [80 dst(gi*5+j)][5 src][8 hd]
  float* sss = (float*)(smem + 136960);   // [80][8]
  float* ssd = (float*)(smem + 139520);   // [80][8]
  const f32x4 zz = {0.f, 0.f, 0.f, 0.f};
  f32x4 acc[5][2], asc[5];
#pragma unroll
  for (int mt = 0; mt < 5; ++mt) { acc[mt][0] = zz; acc[mt][1] = zz; asc[mt] = zz; }

  // ================= PHASE 1: layer-1 GEMM (single K-tile) ==================
  {
#pragma unroll
    for (int r_ = 0; r_ < 2; ++r_) {
      int c_ = t + r_ * 1024; int row_ = c_ >> 2;
      int sw_ = ((((c_ & 3) ^ (row_ & 3) ^ ((row_ >> 2) & 3)) & 3)) * 8;
      GLL(W1T32 + (size_t)row_ * 32 + sw_, smem + 81920 + c_ * 16);
    }
    if (t < 320) {
      int c_ = t; int row_ = c_ >> 2;
      int sw_ = ((((c_ & 3) ^ (row_ & 3) ^ ((row_ >> 2) & 3)) & 3)) * 8;
      GLL(xpad32 + (size_t)(m0 + row_) * 32 + sw_, smem + 114688 + c_ * 16);
    } else if (t < 384) {
      int c_ = t - 320; int row_ = c_ >> 2;
      int sw_ = ((((c_ & 3) ^ (row_ & 3) ^ ((row_ >> 2) & 3)) & 3)) * 8;
      GLL(wsc1T + (size_t)row_ * 32 + sw_, smem + 119808 + c_ * 16);
    }
  }
  asm volatile("s_waitcnt vmcnt(0)" ::: "memory");
  __builtin_amdgcn_s_barrier();
  {
    const char* bb = smem + 81920;
    const char* aa = smem + 114688;
    const char* sb = smem + 119808;
    frag8 af[5], bfr[2];
#pragma unroll
    for (int mt = 0; mt < 5; ++mt)
      af[mt] = *(const frag8*)(aa + (mt * 16 + l15) * 64 + ko2);
#pragma unroll
    for (int n = 0; n < 2; ++n)
      bfr[n] = *(const frag8*)(bb + ((2 * w + n) * 16 + l15) * 64 + ko2);
#pragma unroll
    for (int mt = 0; mt < 5; ++mt)
#pragma unroll
      for (int n = 0; n < 2; ++n)
        acc[mt][n] = __builtin_amdgcn_mfma_f32_16x16x32_bf16(af[mt], bfr[n], acc[mt][n], 0, 0, 0);
    if (w == 15) {
      frag8 sfr = *(const frag8*)(sb + l15 * 64 + ko2);
#pragma unroll
      for (int mt = 0; mt < 5; ++mt)
        asc[mt] = __builtin_amdgcn_mfma_f32_16x16x32_bf16(af[mt], sfr, asc[mt], 0, 0, 0);
    }
  }
  if (w == 15) {
    float* dst = (l15 & 1) ? ssd : sss;
    int hd = l15 >> 1;
    int q4 = (lane >> 4) * 4;
#pragma unroll
    for (int mt = 0; mt < 5; ++mt)
#pragma unroll
      for (int r = 0; r < 4; ++r)
        dst[(mt * 16 + q4 + r) * 8 + hd] = asc[mt][r];
  }
  __syncthreads();
  // alpha-1: 640 units (gi, dst j, hd)
  if (t < 640) {
    int gi = t / 40, jh = t % 40;
    int j = jh >> 3, hd = jh & 7;
    int g = g0 + gi;
    float sdj = ssd[(gi * 5 + j) * 8 + hd];
    float ce = sce[hd];
    float lg[5], mx = -1e30f;
#pragma unroll
    for (int i = 0; i < 5; ++i) {
      float l = sss[(gi * 5 + i) * 8 + hd] + sdj;
      if (i != j) l = fmaf(eattr[(size_t)g * 20 + i * 4 + (j > i ? j - 1 : j)], ce, l);
      l = l > 0.f ? l : 0.2f * l;      // leaky_relu(0.2)
      lg[i] = l; mx = fmaxf(mx, l);
    }
    float s = 0.f;
#pragma unroll
    for (int i = 0; i < 5; ++i) { lg[i] = __expf(lg[i] - mx); s += lg[i]; }
    float inv = 1.f / (s + 1e-16f);
#pragma unroll
    for (int i = 0; i < 5; ++i) sal[((gi * 5 + j) * 5 + i) * 8 + hd] = lg[i] * inv;
  }
  __syncthreads();
  // epilogue-1: 4 passes of 128 cols; combine -> h1buf (LDS, swizzled chunks)
  {
    float* hbf = (float*)(smem + 81920);   // [80][132]
#pragma unroll
    for (int p = 0; p < 4; ++p) {
      if ((w >> 2) == p) {
        int q4 = (lane >> 4) * 4;
#pragma unroll
        for (int mt = 0; mt < 5; ++mt)
#pragma unroll
          for (int n = 0; n < 2; ++n) {
            int lc = (w & 3) * 32 + n * 16 + l15;
#pragma unroll
            for (int r = 0; r < 4; ++r)
              hbf[(mt * 16 + q4 + r) * 132 + lc] = acc[mt][n][r];
          }
      }
      __syncthreads();
      if (t < 512) {
        int gi = t >> 5, cq = t & 31;
        int hd = 2 * p + (cq >> 4);
        int cg = p * 128 + cq * 4;
        float hv[5][4];
#pragma unroll
        for (int i = 0; i < 5; ++i)
          *(float4*)hv[i] = *(const float4*)&hbf[(gi * 5 + i) * 132 + cq * 4];
        float4 bb4 = *(const float4*)&b1[cg];
        int chunk = cg >> 5, slot = (cg >> 3) & 3, boff = (cg & 7) * 2;
#pragma unroll
        for (int j = 0; j < 5; ++j) {
          float o0 = bb4.x, o1 = bb4.y, o2 = bb4.z, o3 = bb4.w;
#pragma unroll
          for (int i = 0; i < 5; ++i) {
            float a = sal[((gi * 5 + j) * 5 + i) * 8 + hd];
            o0 = fmaf(a, hv[i][0], o0); o1 = fmaf(a, hv[i][1], o1);
            o2 = fmaf(a, hv[i][2], o2); o3 = fmaf(a, hv[i][3], o3);
          }
          o0 = fmaxf(o0, 0.f); o1 = fmaxf(o1, 0.f);
          o2 = fmaxf(o2, 0.f); o3 = fmaxf(o3, 0.f);
          uint2 wv_;
          wv_.x = (uint_t)f2bf(o0) | ((uint_t)f2bf(o1) << 16);
          wv_.y = (uint_t)f2bf(o2) | ((uint_t)f2bf(o3) << 16);
          int row = gi * 5 + j;
          int phys = slot ^ (row & 3) ^ ((row >> 2) & 3);
          *(uint2*)((char*)h1buf + chunk * 5120 + row * 64 + phys * 16 + boff) = wv_;
        }
      }
      __syncthreads();
    }
  }

  // ========= PHASE 2: layer-2 GEMM (K=512), T3-minimum single barrier ======
#pragma unroll
  for (int mt = 0; mt < 5; ++mt) { acc[mt][0] = zz; acc[mt][1] = zz; asc[mt] = zz; }
#define FS2(bi, kk0)                                                           \
  {                                                                            \
    char* bb_ = smem + 81920 + (bi) * 32768;                                   \
    char* sb_ = smem + 147456 + (bi) * 1024;                                   \
    _Pragma("unroll")                                                          \
    for (int r_ = 0; r_ < 2; ++r_) {                                           \
      int c_ = t + r_ * 1024; int row_ = c_ >> 2;                              \
      int sw_ = ((((c_ & 3) ^ (row_ & 3) ^ ((row_ >> 2) & 3)) & 3)) * 8;       \
      GLL(W2T + (size_t)row_ * 512 + (kk0) + sw_, bb_ + c_ * 16);              \
    }                                                                          \
    if (t < 64) {                                                              \
      int c_ = t; int row_ = c_ >> 2;                                          \
      int sw_ = ((((c_ & 3) ^ (row_ & 3) ^ ((row_ >> 2) & 3)) & 3)) * 8;       \
      GLL(wsc2T + (size_t)row_ * 512 + (kk0) + sw_, sb_ + c_ * 16);            \
    }                                                                          \
  }
  FS2(0, 0);
  asm volatile("s_waitcnt vmcnt(0)" ::: "memory");
  __builtin_amdgcn_s_barrier();
  for (int ts = 0; ts < 16; ++ts) {
    int cur = ts & 1;
    if (ts + 1 < 16) FS2(cur ^ 1, (ts + 1) * 32);
    const char* bb = smem + 81920 + cur * 32768;
    const char* aa = (const char*)h1buf + ts * 5120;
    const char* sb = smem + 147456 + cur * 1024;
    frag8 af[5], bfr[2];
#pragma unroll
    for (int mt = 0; mt < 5; ++mt)
      af[mt] = *(const frag8*)(aa + (mt * 16 + l15) * 64 + ko2);
#pragma unroll
    for (int n = 0; n < 2; ++n)
      bfr[n] = *(const frag8*)(bb + ((2 * w + n) * 16 + l15) * 64 + ko2);
    __builtin_amdgcn_s_setprio(1);
#pragma unroll
    for (int mt = 0; mt < 5; ++mt)
#pragma unroll
      for (int n = 0; n < 2; ++n)
        acc[mt][n] = __builtin_amdgcn_mfma_f32_16x16x32_bf16(af[mt], bfr[n], acc[mt][n], 0, 0, 0);
    if (w == 15) {
      frag8 sfr = *(const frag8*)(sb + l15 * 64 + ko2);
#pragma unroll
      for (int mt = 0; mt < 5; ++mt)
        asc[mt] = __builtin_amdgcn_mfma_f32_16x16x32_bf16(af[mt], sfr, asc[mt], 0, 0, 0);
    }
    __builtin_amdgcn_s_setprio(0);
    __builtin_amdgcn_sched_barrier(0);
    asm volatile("s_waitcnt vmcnt(0)" ::: "memory");
    __builtin_amdgcn_s_barrier();
  }
#undef FS2
  if (w == 15) {
    float* dst = (l15 & 1) ? ssd : sss;
    int hd = l15 >> 1;
    int q4 = (lane >> 4) * 4;
#pragma unroll
    for (int mt = 0; mt < 5; ++mt)
#pragma unroll
      for (int r = 0; r < 4; ++r)
        dst[(mt * 16 + q4 + r) * 8 + hd] = asc[mt][r];
  }
  __syncthreads();
  // alpha-2
  if (t < 640) {
    int gi = t / 40, jh = t % 40;
    int j = jh >> 3, hd = jh & 7;
    int g = g0 + gi;
    float sdj = ssd[(gi * 5 + j) * 8 + hd];
    float ce = sce[8 + hd];
    float lg[5], mx = -1e30f;
#pragma unroll
    for (int i = 0; i < 5; ++i) {
      float l = sss[(gi * 5 + i) * 8 + hd] + sdj;
      if (i != j) l = fmaf(eattr[(size_t)g * 20 + i * 4 + (j > i ? j - 1 : j)], ce, l);
      l = l > 0.f ? l : 0.2f * l;
      lg[i] = l; mx = fmaxf(mx, l);
    }
    float s = 0.f;
#pragma unroll
    for (int i = 0; i < 5; ++i) { lg[i] = __expf(lg[i] - mx); s += lg[i]; }
    float inv = 1.f / (s + 1e-16f);
#pragma unroll
    for (int i = 0; i < 5; ++i) sal[((gi * 5 + j) * 5 + i) * 8 + hd] = lg[i] * inv;
  }
  __syncthreads();
  // epilogue-2: 4 passes of 128 cols; combine -> h2 + gmean (global)
  {
    float* hbf = (float*)(smem + 81920);   // [80][132]
#pragma unroll
    for (int p = 0; p < 4; ++p) {
      if ((w >> 2) == p) {
        int q4 = (lane >> 4) * 4;
#pragma unroll
        for (int mt = 0; mt < 5; ++mt)
#pragma unroll
          for (int n = 0; n < 2; ++n) {
            int lc = (w & 3) * 32 + n * 16 + l15;
#pragma unroll
            for (int r = 0; r < 4; ++r)
              hbf[(mt * 16 + q4 + r) * 132 + lc] = acc[mt][n][r];
          }
      }
      __syncthreads();
      if (t < 512) {
        int gi = t >> 5, cq = t & 31;
        int hd = 2 * p + (cq >> 4);
        int cg = p * 128 + cq * 4;
        float hv[5][4];
#pragma unroll
        for (int i = 0; i < 5; ++i)
          *(float4*)hv[i] = *(const float4*)&hbf[(gi * 5 + i) * 132 + cq * 4];
        float4 bb4 = *(const float4*)&b2[cg];
        float gs0 = 0.f, gs1 = 0.f, gs2 = 0.f, gs3 = 0.f;
#pragma unroll
        for (int j = 0; j < 5; ++j) {
          float o0 = bb4.x, o1 = bb4.y, o2 = bb4.z, o3 = bb4.w;
#pragma unroll
          for (int i = 0; i < 5; ++i) {
            float a = sal[((gi * 5 + j) * 5 + i) * 8 + hd];
            o0 = fmaf(a, hv[i][0], o0); o1 = fmaf(a, hv[i][1], o1);
            o2 = fmaf(a, hv[i][2], o2); o3 = fmaf(a, hv[i][3], o3);
          }
          o0 = fmaxf(o0, 0.f); o1 = fmaxf(o1, 0.f);
          o2 = fmaxf(o2, 0.f); o3 = fmaxf(o3, 0.f);
          uint2 wv_;
          wv_.x = (uint_t)f2bf(o0) | ((uint_t)f2bf(o1) << 16);
          wv_.y = (uint_t)f2bf(o2) | ((uint_t)f2bf(o3) << 16);
          *(uint2*)(h2 + ((size_t)(g0 + gi) * 5 + j) * 512 + cg) = wv_;
          gs0 += o0; gs1 += o1; gs2 += o2; gs3 += o3;
        }
        uint2 wv_;
        wv_.x = (uint_t)f2bf(gs0 * 0.2f) | ((uint_t)f2bf(gs1 * 0.2f) << 16);
        wv_.y = (uint_t)f2bf(gs2 * 0.2f) | ((uint_t)f2bf(gs3 * 0.2f) << 16);
        *(uint2*)(gmean + (size_t)(g0 + gi) * 512 + cg) = wv_;
      }
      __syncthreads();
    }
  }
}

// ---------------------------------------------------------------------------
// bf16 MFMA GEMM body, T3-minimum single-barrier schedule (2 buffers, 32 KB):
// {STAGE(next) -> ds_read -> MFMA -> vmcnt(0) -> barrier} per K-step.
// bf16 output. EPI: 1 = plain; 2 = +bias, relu(col<320).
// ---------------------------------------------------------------------------
template <int EPI>
__device__ __forceinline__ void gemm_body(
    const ushort_t* __restrict__ A, const ushort_t* __restrict__ BT,
    const float* __restrict__ bias, ushort_t* __restrict__ Cv,
    int M, int N, int K, int m0, int n0, char* lds) {
  int t = threadIdx.x;
  int lane = t & 63;
  int wv = t >> 6;
  int wr = (wv >> 1) * 64, wc = (wv & 1) * 64;
  f32x4 acc[4][4] = {};
  int ch0 = t, ch1 = t + 256;
  int row0 = ch0 >> 2, row1 = ch1 >> 2;
  int sw0 = (((ch0 & 3) ^ (row0 & 3) ^ ((row0 >> 2) & 3)) & 3) * 8;
  int sw1 = (((ch1 & 3) ^ (row1 & 3) ^ ((row1 >> 2) & 3)) & 3) * 8;
  int ko2 = ((((lane >> 4) ^ (lane & 3) ^ ((lane >> 2) & 3)) & 3) * 16);
  const int nt = K >> 5;
#define STAGE(bi, kk0)                                                         \
  {                                                                            \
    char* ab = lds + (bi) * 16384;                                             \
    GLL(A + (size_t)(m0 + row0) * K + (kk0) + sw0, ab + ch0 * 16);             \
    GLL(A + (size_t)(m0 + row1) * K + (kk0) + sw1, ab + ch1 * 16);             \
    GLL(BT + (size_t)(n0 + row0) * K + (kk0) + sw0, ab + 8192 + ch0 * 16);     \
    GLL(BT + (size_t)(n0 + row1) * K + (kk0) + sw1, ab + 8192 + ch1 * 16);     \
  }
  STAGE(0, 0);
  asm volatile("s_waitcnt vmcnt(0)" ::: "memory");
  __builtin_amdgcn_s_barrier();
  for (int ts = 0; ts < nt; ++ts) {
    int cur = ts & 1;
    // stage next into the buffer consumed two iterations ago (safe: the
    // end-of-previous-iteration barrier proves all waves finished it).
    if (ts + 1 < nt) STAGE(cur ^ 1, (ts + 1) * 32);
    const char* ab = lds + cur * 16384;
    frag8 af[4], bfr[4];
#pragma unroll
    for (int m = 0; m < 4; ++m)
      af[m] = *(const frag8*)(ab + (wr + m * 16 + (lane & 15)) * 64 + ko2);
#pragma unroll
    for (int n = 0; n < 4; ++n)
      bfr[n] = *(const frag8*)(ab + 8192 + (wc + n * 16 + (lane & 15)) * 64 + ko2);
    __builtin_amdgcn_s_setprio(1);
#pragma unroll
    for (int m = 0; m < 4; ++m)
#pragma unroll
      for (int n = 0; n < 4; ++n)
        acc[m][n] = __builtin_amdgcn_mfma_f32_16x16x32_bf16(af[m], bfr[n], acc[m][n], 0, 0, 0);
    __builtin_amdgcn_s_setprio(0);
    __builtin_amdgcn_sched_barrier(0);
    asm volatile("s_waitcnt vmcnt(0)" ::: "memory");
    __builtin_amdgcn_s_barrier();
  }
#undef STAGE
  int r4 = (lane >> 4) * 4;
  int cl = lane & 15;
#pragma unroll
  for (int m = 0; m < 4; ++m) {
#pragma unroll
    for (int n = 0; n < 4; ++n) {
      int col = n0 + wc + n * 16 + cl;
      float bb = (EPI == 2) ? bias[col] : 0.f;
#pragma unroll
      for (int r = 0; r < 4; ++r) {
        int row = m0 + wr + m * 16 + r4 + r;
        float v = acc[m][n][r] + bb;
        if (EPI == 2 && col < 320) v = fmaxf(v, 0.f);
        Cv[(size_t)row * N + col] = f2bf(v);
      }
    }
  }
}

// Fused head GEMMs: blocks [0,320) -> ahid = h2 @ aw1topT^T (bf16 out);
// blocks [320,576) -> hcat = gmean @ WcatT^T + bcat, relu(col<320), bf16 out.
__global__ __launch_bounds__(256) void k_hgemm(
    const ushort_t* __restrict__ h2, const ushort_t* __restrict__ aw1topT,
    ushort_t* __restrict__ ahid, const ushort_t* __restrict__ gmean,
    const ushort_t* __restrict__ WcatT, const float* __restrict__ bcat,
    ushort_t* __restrict__ hcat) {
  __shared__ char lds[32768];
  int bid = blockIdx.x;
  if (bid < 320) {
    int lid = xcd_swz(bid, 320);
    gemm_body<1>(h2, aw1topT, nullptr, ahid, NN, 128, DD, lid * 128, 0, lds);
  } else {
    int lid = xcd_swz(bid - 320, 256);
    gemm_body<2>(gmean, WcatT, bcat, hcat, GG, DD, DD, (lid >> 2) * 128, (lid & 3) * 128, lds);
  }
}

// ---------------------------------------------------------------------------
// Final heads — bf16 inputs for hcat/ahid.
// ---------------------------------------------------------------------------
__global__ __launch_bounds__(256) void k_heads(
    const ushort_t* __restrict__ hcat, const ushort_t* __restrict__ ahid,
    const float* __restrict__ woutT, const float* __restrict__ bout,
    const float* __restrict__ alim, float* __restrict__ out) {
  int g0 = blockIdx.x * 4;
  int t = threadIdx.x;
  __shared__ float sbuf[4224];
  for (int i = t; i < 4224; i += 256) {
    int gi = i / 1056, r = i - gi * 1056;
    const ushort_t* grow = hcat + (size_t)(g0 + gi) * 512;
    float v = 0.f;
    if (r < 128)                  v = bf2f(grow[r]);
    else if (r >= 132 && r < 260) v = bf2f(grow[128 + r - 132]);
    else if (r >= 264 && r < 328) v = bf2f(grow[256 + r - 264]);
    else if (r >= 396) {
      int q = r - 396; int a = q / 132; int j = q - a * 132;
      if (j < 128)
        v = fmaxf(bf2f(ahid[((size_t)(g0 + gi) * 5 + a) * 128 + j]) + bf2f(grow[320 + j]), 0.f);
    }
    sbuf[i] = v;
  }
  __syncthreads();
  int gi = t >> 6, o = t & 63;
  int oc = o < 39 ? o : 39;
  int seg;
  if (oc < 4)       seg = 0;
  else if (oc < 8)  seg = 132;
  else if (oc == 8) seg = 264;
  else {
    int idx = (oc < 24) ? oc - 9 : oc - 24;
    seg = 396 + (idx / 3) * 132;
  }
  const float* ip = &sbuf[gi * 1056 + seg];
  float a0 = 0.f, a1 = 0.f, a2 = 0.f, a3 = 0.f;
#pragma unroll
  for (int j = 0; j < 128; j += 4) {
    a0 = fmaf(ip[j + 0], woutT[(j + 0) * 40 + oc], a0);
    a1 = fmaf(ip[j + 1], woutT[(j + 1) * 40 + oc], a1);
    a2 = fmaf(ip[j + 2], woutT[(j + 2) * 40 + oc], a2);
    a3 = fmaf(ip[j + 3], woutT[(j + 3) * 40 + oc], a3);
  }
  float res = (a0 + a1) + (a2 + a3) + bout[oc];
  if (o < 39) {
    if (o == 8)       res = 1.f / (1.f + __expf(-res));
    else if (o >= 24) res = 0.05f + 0.45f / (1.f + __expf(-res)) + 1e-6f;
    else if (o >= 9)  res = tanhf(res) * alim[(o - 9) % 3];
    out[(size_t)(g0 + gi) * 39 + o] = res;
  }
}

// ---------------------------------------------------------------------------
extern "C" void kernel_launch(void* const* d_in, const int* in_sizes, int n_in,
                              void* d_out, int out_size, void* d_ws, size_t ws_size,
                              hipStream_t stream) {
  const float* x     = (const float*)d_in[0];
  const float* eattr = (const float*)d_in[1];
  const float* W1  = (const float*)d_in[5];
  const float* as1 = (const float*)d_in[6];
  const float* ad1 = (const float*)d_in[7];
  const float* We1 = (const float*)d_in[8];
  const float* ae1 = (const float*)d_in[9];
  const float* b1  = (const float*)d_in[10];
  const float* W2  = (const float*)d_in[11];
  const float* as2 = (const float*)d_in[12];
  const float* ad2 = (const float*)d_in[13];
  const float* We2 = (const float*)d_in[14];
  const float* ae2 = (const float*)d_in[15];
  const float* b2  = (const float*)d_in[16];
  const float* pw1 = (const float*)d_in[17];
  const float* pb1 = (const float*)d_in[18];
  const float* pw2 = (const float*)d_in[19];
  const float* pb2 = (const float*)d_in[20];
  const float* qw1 = (const float*)d_in[21];
  const float* qb1 = (const float*)d_in[22];
  const float* qw2 = (const float*)d_in[23];
  const float* qb2 = (const float*)d_in[24];
  const float* aw1 = (const float*)d_in[25];
  const float* ab1 = (const float*)d_in[26];
  const float* aw2 = (const float*)d_in[27];
  const float* ab2 = (const float*)d_in[28];
  const float* tw1 = (const float*)d_in[29];
  const float* tb1 = (const float*)d_in[30];
  const float* tw2 = (const float*)d_in[31];
  const float* tb2 = (const float*)d_in[32];
  const float* alim = (const float*)d_in[33];

  const size_t BIGE = (size_t)NN * DD;
  char* p = (char*)d_ws;
  ushort_t* h2     = (ushort_t*)p; p += BIGE * 2;                // 42MB
  ushort_t* gmean  = (ushort_t*)p; p += (size_t)GG * DD * 2;     // 8.4MB
  ushort_t* xpad32 = (ushort_t*)p; p += (size_t)NN * 32 * 2;     // 2.6MB
  ushort_t* W1T32  = (ushort_t*)p; p += (size_t)512 * 32 * 2;
  ushort_t* W2T    = (ushort_t*)p; p += (size_t)512 * 512 * 2;
  ushort_t* WcatT  = (ushort_t*)p; p += (size_t)512 * 512 * 2;
  ushort_t* aw1topT = (ushort_t*)p; p += (size_t)128 * 512 * 2;
  ushort_t* wsc1T  = (ushort_t*)p; p += (size_t)16 * 32 * 2;
  ushort_t* wsc2T  = (ushort_t*)p; p += (size_t)16 * 512 * 2;
  float* bcat  = (float*)p; p += 512 * 4;
  float* sce   = (float*)p; p += 16 * 4;                          // [0,8)=L1 [8,16)=L2
  float* woutT = (float*)p; p += 5120 * 4;
  float* bout  = (float*)p; p += 40 * 4;
  ushort_t* ahid = (ushort_t*)p; p += (size_t)NN * 128 * 2;       // 10.5MB
  ushort_t* hcat = (ushort_t*)p;                                  // 8.4MB

  k_prep<<<1024 + 5120, 256, 0, stream>>>(
      x, W1, W2, pw1, qw1, tw1, aw1, pb1, qb1, tb1, ab1,
      We1, ae1, We2, ae2, as1, ad1, as2, ad2,
      pw2, pb2, qw2, qb2, tw2, tb2, aw2, ab2,
      xpad32, W1T32, W2T, WcatT, aw1topT, wsc1T, wsc2T,
      bcat, sce, woutT, bout);
  // --- both GAT layers fused; h1 never leaves LDS ---
  k_mega<<<GG / 16, 1024, 0, stream>>>(
      xpad32, W1T32, wsc1T, W2T, wsc2T, eattr, sce, b1, b2, h2, gmean);
  // --- heads (fused: ahid + hcat in one launch, bf16 out) ---
  k_hgemm<<<320 + 256, 256, 0, stream>>>(h2, aw1topT, ahid, gmean, WcatT, bcat, hcat);
  k_heads<<<GG / 4, 256, 0, stream>>>(hcat, ahid, woutT, bout, alim, (float*)d_out);
}